// Round 2
// baseline (222.337 us; speedup 1.0000x reference)
//
#include <hip/hip_runtime.h>
#include <hip/hip_bf16.h>
#include <cstdint>
#include <cstddef>

typedef __attribute__((ext_vector_type(8))) short bf16x8;
typedef __attribute__((ext_vector_type(4))) float f32x4;

constexpr int Bc = 2, Sc = 2048, Dc = 512, Hc = 8, DKc = 64;

struct alignas(16) us8 { unsigned short u[8]; };

__device__ __forceinline__ unsigned short f2bf(float x) {
  union { float f; unsigned int u; } v; v.f = x;
  unsigned int r = (v.u + 0x7FFFu + ((v.u >> 16) & 1u)) >> 16;
  return (unsigned short)r;
}

__device__ __forceinline__ float bf2f(unsigned short u) {
  union { unsigned int u; float f; } v; v.u = ((unsigned int)u) << 16;
  return v.f;
}

__device__ __forceinline__ us8 cvt8(float4 a, float4 b) {
  us8 o;
  o.u[0] = f2bf(a.x); o.u[1] = f2bf(a.y); o.u[2] = f2bf(a.z); o.u[3] = f2bf(a.w);
  o.u[4] = f2bf(b.x); o.u[5] = f2bf(b.y); o.u[6] = f2bf(b.z); o.u[7] = f2bf(b.w);
  return o;
}

// ---------------- prepass: group_prob fp32 -> bf16 ----------------
__global__ __launch_bounds__(256)
void cvt_g(const float* __restrict__ g, unsigned short* __restrict__ out, int n8)
{
  int i = blockIdx.x * blockDim.x + threadIdx.x;
  const int stride = gridDim.x * blockDim.x;
  for (; i < n8; i += stride) {
    float4 a = ((const float4*)g)[(size_t)i * 2];
    float4 b = ((const float4*)g)[(size_t)i * 2 + 1];
    ((us8*)out)[i] = cvt8(a, b);
  }
}

// ---------------- prepass: mask int32 -> bits (diag OR-folded) ----------------
__global__ __launch_bounds__(256)
void cvt_mask(const int* __restrict__ m, unsigned long long* __restrict__ out, int ngroups)
{
  const int lane = threadIdx.x & 63;
  int gid = (blockIdx.x * blockDim.x + threadIdx.x) >> 6;
  const int stride = (gridDim.x * blockDim.x) >> 6;
  for (; gid < ngroups; gid += stride) {
    const size_t base = (size_t)gid * 64;
    const int rem = (int)(base & ((size_t)Sc * Sc - 1));
    const int srow = rem >> 11;                  // row within [S,S]
    const int k = (rem & (Sc - 1)) + lane;       // col
    const bool pred = (m[base + lane] != 0) || (k == srow);
    unsigned long long bal = __ballot(pred);
    if (lane == 0) out[gid] = bal;
  }
}

// C = A * W^T + bias.  A: [M,K] (fp32 or bf16), W: [N,K] fp32 (converted to bf16 in staging).
// OUT_MODE 0: bf16 row-major [M,N]; 1: bf16 transposed per batch -> [b][n][s] (V^T); 2: fp32 [M,N].
template<int A_BF16, int OUT_MODE>
__global__ __launch_bounds__(256)
void gemm_nt(const void* __restrict__ Ap, const float* __restrict__ Wp,
             const float* __restrict__ bias, void* __restrict__ Cp,
             int M, int N, int K)
{
  constexpr int KC = 32;
  __shared__ unsigned short As[64][KC + 8];
  __shared__ unsigned short Bs[64][KC + 8];
  const int tid = threadIdx.x;
  const int lane = tid & 63, wid = tid >> 6;
  const int m0 = blockIdx.x * 64, n0 = blockIdx.y * 64;

  f32x4 acc[4] = {{0,0,0,0},{0,0,0,0},{0,0,0,0},{0,0,0,0}};

  const int r = tid >> 2;
  const int c = (tid & 3) * 8;

  for (int k0 = 0; k0 < K; k0 += KC) {
    __syncthreads();
    if (A_BF16) {
      const unsigned short* A = (const unsigned short*)Ap;
      *(us8*)&As[r][c] = *(const us8*)(A + (size_t)(m0 + r) * K + k0 + c);
    } else {
      const float* A = (const float*)Ap;
      const float* p = A + (size_t)(m0 + r) * K + k0 + c;
      float4 v0 = *(const float4*)p, v1 = *(const float4*)(p + 4);
      *(us8*)&As[r][c] = cvt8(v0, v1);
    }
    {
      const float* p = Wp + (size_t)(n0 + r) * K + k0 + c;
      float4 v0 = *(const float4*)p, v1 = *(const float4*)(p + 4);
      *(us8*)&Bs[r][c] = cvt8(v0, v1);
    }
    __syncthreads();
    bf16x8 af = *(const bf16x8*)&As[wid * 16 + (lane & 15)][(lane >> 4) * 8];
#pragma unroll
    for (int n = 0; n < 4; ++n) {
      bf16x8 bfv = *(const bf16x8*)&Bs[n * 16 + (lane & 15)][(lane >> 4) * 8];
      acc[n] = __builtin_amdgcn_mfma_f32_16x16x32_bf16(af, bfv, acc[n], 0, 0, 0);
    }
  }

  const int colb = lane & 15;
  const int rowb = (lane >> 4) * 4;
#pragma unroll
  for (int n = 0; n < 4; ++n) {
    const int gn = n0 + n * 16 + colb;
    const float bv = bias[gn];
#pragma unroll
    for (int rr = 0; rr < 4; ++rr) {
      const int gm = m0 + wid * 16 + rowb + rr;
      const float y = acc[n][rr] + bv;
      if (OUT_MODE == 0) {
        ((unsigned short*)Cp)[(size_t)gm * N + gn] = f2bf(y);
      } else if (OUT_MODE == 1) {
        const int bb = gm >> 11, ss = gm & (Sc - 1);
        ((unsigned short*)Cp)[((size_t)bb * N + gn) * Sc + ss] = f2bf(y);
      } else {
        ((float*)Cp)[(size_t)gm * N + gn] = y;
      }
    }
  }
}

// Flash-style attention, one (b,h) x 64-row q tile per block, 4 waves.
// Qb,Kb: bf16 [B,S,D]; Vt: bf16 [B,D,S]; Gb: bf16 [B,S,S]; Mb: u64 bits [B,S,S/64];
// Xb out: bf16 [B,S,D].
__global__ __launch_bounds__(256, 4)
void attn_kernel(const unsigned short* __restrict__ Qb,
                 const unsigned short* __restrict__ Kb,
                 const unsigned short* __restrict__ Vt,
                 const unsigned short* __restrict__ Gb,
                 const unsigned long long* __restrict__ Mb,
                 unsigned short* __restrict__ Xb)
{
  __shared__ unsigned short Ks[64][72];
  __shared__ unsigned short Vs[64][72];     // [dk][kc]
  __shared__ unsigned short Gs[64][72];     // [q][kc] bf16
  __shared__ unsigned long long Mw[64];     // per q-row bit-mask for this k-tile
  __shared__ unsigned short Ps[4][16][72];  // per-wave private

  const int tid = threadIdx.x, lane = tid & 63, wid = tid >> 6;
  const int bh = blockIdx.x, b = bh >> 3, h = bh & 7;
  const int q0 = blockIdx.y * 64;

  const int r = tid >> 2;            // 0..63
  const int c = (tid & 3) * 16;      // 0,16,32,48

  const int colb = lane & 15;
  const int hi = lane >> 4;
  const int rowb = hi * 4;

  // Q fragments straight from global (each wave owns q-rows wid*16..+15)
  bf16x8 qf[2];
  {
    const unsigned short* qp = Qb + ((size_t)(b * Sc + q0 + wid * 16 + colb) * Dc + h * DKc + hi * 8);
    qf[0] = *(const bf16x8*)qp;
    qf[1] = *(const bf16x8*)(qp + 32);
  }

  f32x4 acc[4] = {{0,0,0,0},{0,0,0,0},{0,0,0,0},{0,0,0,0}};
  float mrun[4] = {-1e30f, -1e30f, -1e30f, -1e30f};
  float lrun[4] = {0.f, 0.f, 0.f, 0.f};

  us8 kreg[2], vreg[2], greg[2];
  unsigned long long mreg = 0;

  auto preload = [&](int kt) {
    const int k0 = kt * 64;
    const unsigned short* kp = Kb + ((size_t)(b * Sc + k0 + r) * Dc + h * DKc + c);
    kreg[0] = *(const us8*)kp;
    kreg[1] = *(const us8*)(kp + 8);
    const unsigned short* vp = Vt + ((size_t)(b * Dc + h * DKc + r) * Sc + k0 + c);
    vreg[0] = *(const us8*)vp;
    vreg[1] = *(const us8*)(vp + 8);
    const unsigned short* gp = Gb + ((size_t)(b * Sc + q0 + r) * Sc + k0 + c);
    greg[0] = *(const us8*)gp;
    greg[1] = *(const us8*)(gp + 8);
    if (tid < 64) mreg = Mb[((size_t)(b * Sc + q0 + tid)) * (Sc / 64) + kt];
  };

  preload(0);

  constexpr int NT = Sc / 64;
  for (int kt = 0; kt < NT; ++kt) {
    __syncthreads();   // previous tile fully consumed
    *(us8*)&Ks[r][c]     = kreg[0];
    *(us8*)&Ks[r][c + 8] = kreg[1];
    *(us8*)&Vs[r][c]     = vreg[0];
    *(us8*)&Vs[r][c + 8] = vreg[1];
    *(us8*)&Gs[r][c]     = greg[0];
    *(us8*)&Gs[r][c + 8] = greg[1];
    if (tid < 64) Mw[tid] = mreg;
    __syncthreads();   // staged

    if (kt + 1 < NT) preload(kt + 1);   // overlap next tile's HBM latency with compute

    // S = Q K^T
    f32x4 sf[4] = {{0,0,0,0},{0,0,0,0},{0,0,0,0},{0,0,0,0}};
#pragma unroll
    for (int kk = 0; kk < 2; ++kk) {
#pragma unroll
      for (int n = 0; n < 4; ++n) {
        bf16x8 bfv = *(const bf16x8*)&Ks[n * 16 + colb][kk * 32 + hi * 8];
        sf[n] = __builtin_amdgcn_mfma_f32_16x16x32_bf16(qf[kk], bfv, sf[n], 0, 0, 0);
      }
    }

    // scale + mask (mask bits already include the diagonal)
    unsigned long long wsh[4];
#pragma unroll
    for (int rr = 0; rr < 4; ++rr)
      wsh[rr] = Mw[wid * 16 + rowb + rr] >> colb;   // broadcast read
#pragma unroll
    for (int n = 0; n < 4; ++n) {
#pragma unroll
      for (int rr = 0; rr < 4; ++rr) {
        const bool allowed = ((unsigned int)(wsh[rr] >> (16 * n)) & 1u) != 0u;
        sf[n][rr] = allowed ? sf[n][rr] * 0.125f : -1e30f;
      }
    }

    // online softmax stats (rows live in 16-lane shuffle groups)
    float mnew[4], alpha[4], rsum[4];
#pragma unroll
    for (int rr = 0; rr < 4; ++rr) {
      float tm = fmaxf(fmaxf(sf[0][rr], sf[1][rr]), fmaxf(sf[2][rr], sf[3][rr]));
      tm = fmaxf(tm, __shfl_xor(tm, 1));
      tm = fmaxf(tm, __shfl_xor(tm, 2));
      tm = fmaxf(tm, __shfl_xor(tm, 4));
      tm = fmaxf(tm, __shfl_xor(tm, 8));
      const float mn = fmaxf(mrun[rr], tm);
      mnew[rr] = mn;
      alpha[rr] = __expf(mrun[rr] - mn);
      mrun[rr] = mn;
      rsum[rr] = 0.f;
    }

    // p = exp(s - m); l += p; Ps = bf16(p * g)
#pragma unroll
    for (int n = 0; n < 4; ++n) {
#pragma unroll
      for (int rr = 0; rr < 4; ++rr) {
        const int qi = wid * 16 + rowb + rr;
        const int kj = n * 16 + colb;
        const float p = __expf(sf[n][rr] - mnew[rr]);
        rsum[rr] += p;
        const float pg = p * bf2f(Gs[qi][kj]);
        Ps[wid][rowb + rr][kj] = f2bf(pg);
      }
    }
#pragma unroll
    for (int rr = 0; rr < 4; ++rr) {
      float s = rsum[rr];
      s += __shfl_xor(s, 1);
      s += __shfl_xor(s, 2);
      s += __shfl_xor(s, 4);
      s += __shfl_xor(s, 8);
      lrun[rr] = lrun[rr] * alpha[rr] + s;
    }

    // acc = acc*alpha + (P*g) @ V   (Ps is wave-private: in-wave lgkmcnt ordering suffices)
#pragma unroll
    for (int n = 0; n < 4; ++n)
#pragma unroll
      for (int rr = 0; rr < 4; ++rr) acc[n][rr] *= alpha[rr];
#pragma unroll
    for (int kk = 0; kk < 2; ++kk) {
      bf16x8 af = *(const bf16x8*)&Ps[wid][colb][kk * 32 + hi * 8];
#pragma unroll
      for (int n = 0; n < 4; ++n) {
        bf16x8 bfv = *(const bf16x8*)&Vs[n * 16 + colb][kk * 32 + hi * 8];
        acc[n] = __builtin_amdgcn_mfma_f32_16x16x32_bf16(af, bfv, acc[n], 0, 0, 0);
      }
    }
  }

  // epilogue: x = acc / l  -> bf16 [B,S,D]
#pragma unroll
  for (int n = 0; n < 4; ++n) {
#pragma unroll
    for (int rr = 0; rr < 4; ++rr) {
      const int qi = wid * 16 + rowb + rr;
      const float y = acc[n][rr] / lrun[rr];
      Xb[(size_t)(b * Sc + q0 + qi) * Dc + h * DKc + n * 16 + colb] = f2bf(y);
    }
  }
}

extern "C" void kernel_launch(void* const* d_in, const int* in_sizes, int n_in,
                              void* d_out, int out_size, void* d_ws, size_t ws_size,
                              hipStream_t stream)
{
  const float* query = (const float*)d_in[0];
  const float* key_  = (const float*)d_in[1];
  const float* value = (const float*)d_in[2];
  const float* gprob = (const float*)d_in[3];
  const int*   mask  = (const int*)d_in[4];
  const float* Wq = (const float*)d_in[5];
  const float* bq = (const float*)d_in[6];
  const float* Wk = (const float*)d_in[7];
  const float* bk = (const float*)d_in[8];
  const float* Wv = (const float*)d_in[9];
  const float* bv = (const float*)d_in[10];
  const float* Wo = (const float*)d_in[11];
  const float* bo = (const float*)d_in[12];
  float* out = (float*)d_out;

  const size_t elems = (size_t)Bc * Sc * Dc;     // 2*2048*512
  const size_t gelems = (size_t)Bc * Sc * Sc;    // 2*2048*2048
  unsigned short* Qb = (unsigned short*)d_ws;
  unsigned short* Kb = Qb + elems;
  unsigned short* Vt = Kb + elems;
  unsigned short* Xb = Vt + elems;
  unsigned short* Gb = Xb + elems;
  unsigned long long* Mbits = (unsigned long long*)(Gb + gelems);

  // prepasses
  hipLaunchKernelGGL(cvt_g, dim3(2048), dim3(256), 0, stream, gprob, Gb, (int)(gelems / 8));
  hipLaunchKernelGGL(cvt_mask, dim3(2048), dim3(256), 0, stream, mask, Mbits, (int)(gelems / 64));

  const int M = Bc * Sc, N = Dc, K = Dc;
  dim3 gg(M / 64, N / 64), blk(256);

  hipLaunchKernelGGL((gemm_nt<0, 0>), gg, blk, 0, stream, (const void*)query, Wq, bq, (void*)Qb, M, N, K);
  hipLaunchKernelGGL((gemm_nt<0, 0>), gg, blk, 0, stream, (const void*)key_,  Wk, bk, (void*)Kb, M, N, K);
  hipLaunchKernelGGL((gemm_nt<0, 1>), gg, blk, 0, stream, (const void*)value, Wv, bv, (void*)Vt, M, N, K);

  dim3 ga(Bc * Hc, Sc / 64);
  hipLaunchKernelGGL(attn_kernel, ga, blk, 0, stream, Qb, Kb, Vt, Gb, Mbits, Xb);

  hipLaunchKernelGGL((gemm_nt<1, 2>), gg, blk, 0, stream, (const void*)Xb, Wo, bo, (void*)out, M, N, K);
}

// Round 3
// 161.368 us; speedup vs baseline: 1.3778x; 1.3778x over previous
//
#include <hip/hip_runtime.h>
#include <hip/hip_bf16.h>
#include <cstdint>
#include <cstddef>

typedef __attribute__((ext_vector_type(8))) short bf16x8;
typedef __attribute__((ext_vector_type(4))) float f32x4;
typedef __attribute__((address_space(3))) void lds_void;
typedef const __attribute__((address_space(1))) void g_void;

constexpr int Bc = 2, Sc = 2048, Dc = 512, Hc = 8, DKc = 64;
constexpr int SPLIT = 2;
constexpr int NKT = Sc / 64;           // 32 k-tiles total
constexpr int KT_PER = NKT / SPLIT;    // 16 per block

struct alignas(16) us8 { unsigned short u[8]; };

__device__ __forceinline__ unsigned short f2bf(float x) {
  union { float f; unsigned int u; } v; v.f = x;
  unsigned int r = (v.u + 0x7FFFu + ((v.u >> 16) & 1u)) >> 16;
  return (unsigned short)r;
}

__device__ __forceinline__ float bf2f(unsigned short u) {
  union { unsigned int u; float f; } v; v.u = ((unsigned int)u) << 16;
  return v.f;
}

__device__ __forceinline__ us8 cvt8(float4 a, float4 b) {
  us8 o;
  o.u[0] = f2bf(a.x); o.u[1] = f2bf(a.y); o.u[2] = f2bf(a.z); o.u[3] = f2bf(a.w);
  o.u[4] = f2bf(b.x); o.u[5] = f2bf(b.y); o.u[6] = f2bf(b.z); o.u[7] = f2bf(b.w);
  return o;
}

// ---------------- prepass: fp32 -> bf16, 8-wide ----------------
__global__ __launch_bounds__(256)
void cvt_bf16(const float* __restrict__ x, unsigned short* __restrict__ out, int n8)
{
  int i = blockIdx.x * blockDim.x + threadIdx.x;
  const int stride = gridDim.x * blockDim.x;
  for (; i < n8; i += stride) {
    float4 a = ((const float4*)x)[(size_t)i * 2];
    float4 b = ((const float4*)x)[(size_t)i * 2 + 1];
    ((us8*)out)[i] = cvt8(a, b);
  }
}

// ---------------- prepass: group_prob fp32 -> bf16 in MFMA C-fragment order ----------------
// out[((b*32+qt)*32+kt)*256*16 + tid*16 + n*4+rr] = g[b][qt*64+qi(tid,rr)][kt*64+kj(tid,n)]
__global__ __launch_bounds__(256)
void cvt_gperm(const float* __restrict__ g, unsigned short* __restrict__ out)
{
  const int idx = blockIdx.x;                 // b*1024 + qt*32 + kt
  const int b = idx >> 10, rest = idx & 1023, qt = rest >> 5, kt = rest & 31;
  const int tid = threadIdx.x;
  const int colb = tid & 15, hi = (tid >> 4) & 3, wid = tid >> 6;
  const int q0 = qt * 64, k0 = kt * 64;
  unsigned short vals[16];
#pragma unroll
  for (int n = 0; n < 4; ++n)
#pragma unroll
    for (int rr = 0; rr < 4; ++rr) {
      const int qi = wid * 16 + hi * 4 + rr, kj = n * 16 + colb;
      vals[n * 4 + rr] = f2bf(g[((size_t)(b * Sc) + q0 + qi) * Sc + k0 + kj]);
    }
  us8* o = (us8*)(out + (((size_t)idx * 256) + tid) * 16);
  o[0] = *(us8*)&vals[0];
  o[1] = *(us8*)&vals[8];
}

// ---------------- prepass: mask int32 -> bits (diag OR-folded) ----------------
__global__ __launch_bounds__(256)
void cvt_mask(const int* __restrict__ m, unsigned long long* __restrict__ out, int ngroups)
{
  const int lane = threadIdx.x & 63;
  int gid = (blockIdx.x * blockDim.x + threadIdx.x) >> 6;
  const int stride = (gridDim.x * blockDim.x) >> 6;
  for (; gid < ngroups; gid += stride) {
    const size_t base = (size_t)gid * 64;
    const int rem = (int)(base & ((size_t)Sc * Sc - 1));
    const int srow = rem >> 11;
    const int k = (rem & (Sc - 1)) + lane;
    const bool pred = (m[base + lane] != 0) || (k == srow);
    unsigned long long bal = __ballot(pred);
    if (lane == 0) out[gid] = bal;
  }
}

// C = A * W^T + bias.  A: [M,K] bf16, W: [N,K] fp32 (converted in staging).
// OUT_MODE 0: bf16 [M,N]; 1: bf16 per-batch transposed -> [b][n][s]; 2: fp32 [M,N].
template<int OUT_MODE>
__global__ __launch_bounds__(256)
void gemm_nt(const unsigned short* __restrict__ Ap, const float* __restrict__ Wp,
             const float* __restrict__ bias, void* __restrict__ Cp,
             int M, int N, int K)
{
  constexpr int KC = 32;
  __shared__ unsigned short As[64][KC + 8];
  __shared__ unsigned short Bs[64][KC + 8];
  const int tid = threadIdx.x;
  const int lane = tid & 63, wid = tid >> 6;
  const int m0 = blockIdx.x * 64, n0 = blockIdx.y * 64;

  f32x4 acc[4] = {{0,0,0,0},{0,0,0,0},{0,0,0,0},{0,0,0,0}};

  const int r = tid >> 2;
  const int c = (tid & 3) * 8;

  for (int k0 = 0; k0 < K; k0 += KC) {
    __syncthreads();
    *(us8*)&As[r][c] = *(const us8*)(Ap + (size_t)(m0 + r) * K + k0 + c);
    {
      const float* p = Wp + (size_t)(n0 + r) * K + k0 + c;
      float4 v0 = *(const float4*)p, v1 = *(const float4*)(p + 4);
      *(us8*)&Bs[r][c] = cvt8(v0, v1);
    }
    __syncthreads();
    bf16x8 af = *(const bf16x8*)&As[wid * 16 + (lane & 15)][(lane >> 4) * 8];
#pragma unroll
    for (int n = 0; n < 4; ++n) {
      bf16x8 bfv = *(const bf16x8*)&Bs[n * 16 + (lane & 15)][(lane >> 4) * 8];
      acc[n] = __builtin_amdgcn_mfma_f32_16x16x32_bf16(af, bfv, acc[n], 0, 0, 0);
    }
  }

  const int colb = lane & 15;
  const int rowb = (lane >> 4) * 4;
#pragma unroll
  for (int n = 0; n < 4; ++n) {
    const int gn = n0 + n * 16 + colb;
    const float bv = bias[gn];
#pragma unroll
    for (int rr = 0; rr < 4; ++rr) {
      const int gm = m0 + wid * 16 + rowb + rr;
      const float y = acc[n][rr] + bv;
      if (OUT_MODE == 0) {
        ((unsigned short*)Cp)[(size_t)gm * N + gn] = f2bf(y);
      } else if (OUT_MODE == 1) {
        const int bb = gm >> 11, ss = gm & (Sc - 1);
        ((unsigned short*)Cp)[((size_t)bb * N + gn) * Sc + ss] = f2bf(y);
      } else {
        ((float*)Cp)[(size_t)gm * N + gn] = y;
      }
    }
  }
}

// ---------------- split-K flash attention ----------------
// grid (B*H, S/64, SPLIT). Writes fp32 partials: Pacc[blk][64][64], Pml[blk][2][64].
__global__ __launch_bounds__(256, 4)
void attn_split(const unsigned short* __restrict__ Qb,
                const unsigned short* __restrict__ Kb,
                const unsigned short* __restrict__ Vt,
                const unsigned short* __restrict__ Gp,
                const unsigned long long* __restrict__ Mb,
                float* __restrict__ Pacc,
                float* __restrict__ Pml)
{
  __shared__ unsigned short Ks[2][64][64];   // [k][dk], XOR-swizzled rows
  __shared__ unsigned short Vs[2][64][64];   // [dk][k], XOR-swizzled rows
  __shared__ unsigned short Ps[4][16][64];   // per-wave P, XOR-swizzled rows

  const int tid = threadIdx.x, lane = tid & 63, wid = tid >> 6;
  const int bh = blockIdx.x, b = bh >> 3, h = bh & 7;
  const int qt = blockIdx.y, q0 = qt * 64;
  const int sp = blockIdx.z;
  const int kt0 = sp * KT_PER;

  const int colb = lane & 15;
  const int hi = lane >> 4;
  const int rowb = hi * 4;

  // Q fragments from global (wave owns q-rows wid*16..+15)
  bf16x8 qf[2];
  {
    const unsigned short* qp = Qb + ((size_t)(b * Sc + q0 + wid * 16 + colb) * Dc + h * DKc + hi * 8);
    qf[0] = *(const bf16x8*)qp;
    qf[1] = *(const bf16x8*)(qp + 32);
  }

  f32x4 acc[4] = {{0,0,0,0},{0,0,0,0},{0,0,0,0},{0,0,0,0}};
  float mrun[4] = {-1e30f, -1e30f, -1e30f, -1e30f};
  float lrun[4] = {0.f, 0.f, 0.f, 0.f};

  // async staging: linear LDS dest, inverse-swizzled global source
  auto stageKV = [&](int bufI, int kt) {
    const int k0 = kt * 64;
#pragma unroll
    for (int i = 0; i < 2; ++i) {
      const int obase = wid * 1024 + i * 4096;            // bytes within 8 KB tile
      const int row = (obase >> 7) + (lane >> 3);         // 0..63
      const int cb = ((lane & 7) * 16) ^ ((row & 7) << 4);
      const unsigned short* ksrc = Kb + (size_t)(b * Sc + k0 + row) * Dc + h * DKc + (cb >> 1);
      const unsigned short* vsrc = Vt + ((size_t)b * Dc + h * DKc + row) * Sc + k0 + (cb >> 1);
      __builtin_amdgcn_global_load_lds((g_void*)ksrc, (lds_void*)((char*)&Ks[bufI][0][0] + obase), 16, 0, 0);
      __builtin_amdgcn_global_load_lds((g_void*)vsrc, (lds_void*)((char*)&Vs[bufI][0][0] + obase), 16, 0, 0);
    }
  };

  us8 gcur0, gcur1;
  auto loadG = [&](int kt, us8& g0, us8& g1) {
    const us8* p = (const us8*)(Gp + (((size_t)(b * 1024 + qt * 32 + kt)) * 256 + tid) * 16);
    g0 = p[0]; g1 = p[1];
  };

  stageKV(0, kt0);
  loadG(kt0, gcur0, gcur1);
  asm volatile("s_waitcnt vmcnt(0)" ::: "memory");
  __syncthreads();

  int buf = 0;
  char* psbase = (char*)&Ps[wid][0][0];

  for (int j = 0; j < KT_PER; ++j) {
    const int kt = kt0 + j;
    us8 gn0, gn1;
    if (j + 1 < KT_PER) {
      stageKV(buf ^ 1, kt + 1);          // async into other buffer
      loadG(kt + 1, gn0, gn1);
    }

    // mask words for this tile (L2-resident, issued early)
    unsigned long long mk[4];
#pragma unroll
    for (int rr = 0; rr < 4; ++rr)
      mk[rr] = Mb[((size_t)(b * Sc) + q0 + wid * 16 + rowb + rr) * NKT + kt];

    // S = Q K^T
    f32x4 sf[4] = {{0,0,0,0},{0,0,0,0},{0,0,0,0},{0,0,0,0}};
    char* ksb = (char*)&Ks[buf][0][0];
#pragma unroll
    for (int kk = 0; kk < 2; ++kk) {
#pragma unroll
      for (int n = 0; n < 4; ++n) {
        const int krow = n * 16 + colb;
        bf16x8 bfv = *(const bf16x8*)(ksb + krow * 128 + ((kk * 64 + hi * 16) ^ ((krow & 7) << 4)));
        sf[n] = __builtin_amdgcn_mfma_f32_16x16x32_bf16(qf[kk], bfv, sf[n], 0, 0, 0);
      }
    }

    // scale + mask (bits already include diagonal)
#pragma unroll
    for (int n = 0; n < 4; ++n) {
#pragma unroll
      for (int rr = 0; rr < 4; ++rr) {
        const bool allowed = ((unsigned int)((mk[rr] >> colb) >> (16 * n)) & 1u) != 0u;
        sf[n][rr] = allowed ? sf[n][rr] * 0.125f : -1e30f;
      }
    }

    // online softmax stats
    float mnew[4], alpha[4], rsum[4];
#pragma unroll
    for (int rr = 0; rr < 4; ++rr) {
      float tm = fmaxf(fmaxf(sf[0][rr], sf[1][rr]), fmaxf(sf[2][rr], sf[3][rr]));
      tm = fmaxf(tm, __shfl_xor(tm, 1));
      tm = fmaxf(tm, __shfl_xor(tm, 2));
      tm = fmaxf(tm, __shfl_xor(tm, 4));
      tm = fmaxf(tm, __shfl_xor(tm, 8));
      const float mn = fmaxf(mrun[rr], tm);
      mnew[rr] = mn;
      alpha[rr] = __expf(mrun[rr] - mn);
      mrun[rr] = mn;
      rsum[rr] = 0.f;
    }

    // p = exp(s-m); l += p; Ps = bf16(p*g)  (g pre-permuted to fragment order)
#pragma unroll
    for (int n = 0; n < 4; ++n) {
#pragma unroll
      for (int rr = 0; rr < 4; ++rr) {
        const int jv = n * 4 + rr;
        const float gv = bf2f(jv < 8 ? gcur0.u[jv] : gcur1.u[jv - 8]);
        const float p = __expf(sf[n][rr] - mnew[rr]);
        rsum[rr] += p;
        const int prow = rowb + rr;
        const int kj = n * 16 + colb;
        *(unsigned short*)(psbase + prow * 128 + ((kj * 2) ^ ((prow & 7) << 4))) = f2bf(p * gv);
      }
    }
#pragma unroll
    for (int rr = 0; rr < 4; ++rr) {
      float s = rsum[rr];
      s += __shfl_xor(s, 1);
      s += __shfl_xor(s, 2);
      s += __shfl_xor(s, 4);
      s += __shfl_xor(s, 8);
      lrun[rr] = lrun[rr] * alpha[rr] + s;
    }

    // acc = acc*alpha + (P*g) @ V   (Ps wave-private; in-wave LDS ordering suffices)
#pragma unroll
    for (int n = 0; n < 4; ++n)
#pragma unroll
      for (int rr = 0; rr < 4; ++rr) acc[n][rr] *= alpha[rr];
    char* vsb = (char*)&Vs[buf][0][0];
#pragma unroll
    for (int kk = 0; kk < 2; ++kk) {
      bf16x8 af = *(const bf16x8*)(psbase + colb * 128 + ((kk * 64 + hi * 16) ^ ((colb & 7) << 4)));
#pragma unroll
      for (int n = 0; n < 4; ++n) {
        const int vrow = n * 16 + colb;
        bf16x8 bfv = *(const bf16x8*)(vsb + vrow * 128 + ((kk * 64 + hi * 16) ^ ((vrow & 7) << 4)));
        acc[n] = __builtin_amdgcn_mfma_f32_16x16x32_bf16(af, bfv, acc[n], 0, 0, 0);
      }
    }

    asm volatile("s_waitcnt vmcnt(0)" ::: "memory");
    __syncthreads();
    buf ^= 1;
    if (j + 1 < KT_PER) { gcur0 = gn0; gcur1 = gn1; }
  }

  // write partials
  const size_t blin = ((size_t)bh * 32 + qt) * SPLIT + sp;
  float* pa = Pacc + blin * 4096;
#pragma unroll
  for (int n = 0; n < 4; ++n)
#pragma unroll
    for (int rr = 0; rr < 4; ++rr)
      pa[(size_t)(wid * 16 + rowb + rr) * 64 + n * 16 + colb] = acc[n][rr];
  if (colb == 0) {
    float* pm = Pml + blin * 128;
#pragma unroll
    for (int rr = 0; rr < 4; ++rr) {
      pm[wid * 16 + rowb + rr] = mrun[rr];
      pm[64 + wid * 16 + rowb + rr] = lrun[rr];
    }
  }
}

// ---------------- recombine split partials -> bf16 X ----------------
__global__ __launch_bounds__(256)
void attn_reduce(const float* __restrict__ Pacc, const float* __restrict__ Pml,
                 unsigned short* __restrict__ Xb)
{
  const int gidx = blockIdx.x;      // bh*32 + qt
  const int bh = gidx >> 5, qt = gidx & 31;
  const int b = bh >> 3, h = bh & 7;
  const int tid = threadIdx.x;
  const int qi = tid >> 2, c0 = (tid & 3) * 16;
  const size_t pb = (size_t)gidx * SPLIT;

  float m[SPLIT], l[SPLIT];
  float mstar = -3.0e38f;
#pragma unroll
  for (int s = 0; s < SPLIT; ++s) {
    m[s] = Pml[(pb + s) * 128 + qi];
    l[s] = Pml[(pb + s) * 128 + 64 + qi];
    mstar = fmaxf(mstar, m[s]);
  }
  float w[SPLIT], denom = 0.f;
#pragma unroll
  for (int s = 0; s < SPLIT; ++s) { w[s] = __expf(m[s] - mstar); denom += w[s] * l[s]; }
  const float inv = 1.0f / denom;

  unsigned short* xp = Xb + ((size_t)(b * Sc) + qt * 64 + qi) * Dc + h * DKc + c0;
#pragma unroll
  for (int j = 0; j < 16; j += 4) {
    float ax = 0, ay = 0, az = 0, aw = 0;
#pragma unroll
    for (int s = 0; s < SPLIT; ++s) {
      float4 v = *(const float4*)(Pacc + (pb + s) * 4096 + (size_t)qi * 64 + c0 + j);
      ax += w[s] * v.x; ay += w[s] * v.y; az += w[s] * v.z; aw += w[s] * v.w;
    }
    xp[j + 0] = f2bf(ax * inv); xp[j + 1] = f2bf(ay * inv);
    xp[j + 2] = f2bf(az * inv); xp[j + 3] = f2bf(aw * inv);
  }
}

extern "C" void kernel_launch(void* const* d_in, const int* in_sizes, int n_in,
                              void* d_out, int out_size, void* d_ws, size_t ws_size,
                              hipStream_t stream)
{
  const float* query = (const float*)d_in[0];
  const float* key_  = (const float*)d_in[1];
  const float* value = (const float*)d_in[2];
  const float* gprob = (const float*)d_in[3];
  const int*   mask  = (const int*)d_in[4];
  const float* Wq = (const float*)d_in[5];
  const float* bq = (const float*)d_in[6];
  const float* Wk = (const float*)d_in[7];
  const float* bk = (const float*)d_in[8];
  const float* Wv = (const float*)d_in[9];
  const float* bv = (const float*)d_in[10];
  const float* Wo = (const float*)d_in[11];
  const float* bo = (const float*)d_in[12];
  float* out = (float*)d_out;

  const size_t elems = (size_t)Bc * Sc * Dc;     // 2 Mi
  const size_t gelems = (size_t)Bc * Sc * Sc;    // 8 Mi

  char* base = (char*)d_ws;
  unsigned short* Qb = (unsigned short*)(base);                    // 4 MB
  unsigned short* Kb = Qb + elems;                                 // 4 MB
  unsigned short* Vt = Kb + elems;                                 // 4 MB
  unsigned short* Xb = Vt + elems;                                 // 4 MB
  unsigned short* Gp = Xb + elems;                                 // 16 MB
  unsigned long long* Mbits = (unsigned long long*)(Gp + gelems);  // 1 MB
  char* shared_region = (char*)(Mbits + gelems / 64);
  // region reused: first as bf16 copies of q/k/v inputs, later as split partials
  unsigned short* Ain = (unsigned short*)shared_region;            // 4 MB
  unsigned short* Bin = Ain + elems;                               // 4 MB
  unsigned short* Cin = Bin + elems;                               // 4 MB
  float* Pacc = (float*)shared_region;                             // 16.8 MB
  float* Pml  = Pacc + (size_t)(Bc * Hc) * 32 * SPLIT * 4096;      // 0.5 MB

  // prepasses
  hipLaunchKernelGGL(cvt_bf16, dim3(1024), dim3(256), 0, stream, query, Ain, (int)(elems / 8));
  hipLaunchKernelGGL(cvt_bf16, dim3(1024), dim3(256), 0, stream, key_,  Bin, (int)(elems / 8));
  hipLaunchKernelGGL(cvt_bf16, dim3(1024), dim3(256), 0, stream, value, Cin, (int)(elems / 8));
  hipLaunchKernelGGL(cvt_gperm, dim3(2048), dim3(256), 0, stream, gprob, Gp);
  hipLaunchKernelGGL(cvt_mask, dim3(2048), dim3(256), 0, stream, mask, Mbits, (int)(gelems / 64));

  const int M = Bc * Sc, N = Dc, K = Dc;
  dim3 gg(M / 64, N / 64), blk(256);
  hipLaunchKernelGGL((gemm_nt<0>), gg, blk, 0, stream, Ain, Wq, bq, (void*)Qb, M, N, K);
  hipLaunchKernelGGL((gemm_nt<0>), gg, blk, 0, stream, Bin, Wk, bk, (void*)Kb, M, N, K);
  hipLaunchKernelGGL((gemm_nt<1>), gg, blk, 0, stream, Cin, Wv, bv, (void*)Vt, M, N, K);

  dim3 ga(Bc * Hc, Sc / 64, SPLIT);
  hipLaunchKernelGGL(attn_split, ga, blk, 0, stream, Qb, Kb, Vt, Gp, Mbits, Pacc, Pml);
  hipLaunchKernelGGL(attn_reduce, dim3(Bc * Hc * 32), blk, 0, stream, Pacc, Pml, Xb);

  hipLaunchKernelGGL((gemm_nt<2>), gg, blk, 0, stream, Xb, Wo, bo, (void*)out, M, N, K);
}

// Round 4
// 140.328 us; speedup vs baseline: 1.5844x; 1.1499x over previous
//
#include <hip/hip_runtime.h>
#include <hip/hip_bf16.h>
#include <cstdint>
#include <cstddef>

typedef __attribute__((ext_vector_type(8))) short bf16x8;
typedef __attribute__((ext_vector_type(4))) float f32x4;
typedef __attribute__((address_space(3))) void lds_void;
typedef const __attribute__((address_space(1))) void g_void;

constexpr int Bc = 2, Sc = 2048, Dc = 512, Hc = 8, DKc = 64;
constexpr int SPLIT = 2;
constexpr int NKT = Sc / 64;           // 32 k-tiles total
constexpr int KT_PER = NKT / SPLIT;    // 16 per block

struct alignas(16) us8 { unsigned short u[8]; };

__device__ __forceinline__ unsigned short f2bf(float x) {
  union { float f; unsigned int u; } v; v.f = x;
  unsigned int r = (v.u + 0x7FFFu + ((v.u >> 16) & 1u)) >> 16;
  return (unsigned short)r;
}

__device__ __forceinline__ float bf2f(unsigned short u) {
  union { unsigned int u; float f; } v; v.u = ((unsigned int)u) << 16;
  return v.f;
}

__device__ __forceinline__ us8 cvt8(float4 a, float4 b) {
  us8 o;
  o.u[0] = f2bf(a.x); o.u[1] = f2bf(a.y); o.u[2] = f2bf(a.z); o.u[3] = f2bf(a.w);
  o.u[4] = f2bf(b.x); o.u[5] = f2bf(b.y); o.u[6] = f2bf(b.z); o.u[7] = f2bf(b.w);
  return o;
}

// ---------------- prepass: fp32 -> bf16, 8-wide ----------------
__global__ __launch_bounds__(256)
void cvt_bf16(const float* __restrict__ x, unsigned short* __restrict__ out, int n8)
{
  int i = blockIdx.x * blockDim.x + threadIdx.x;
  const int stride = gridDim.x * blockDim.x;
  for (; i < n8; i += stride) {
    float4 a = ((const float4*)x)[(size_t)i * 2];
    float4 b = ((const float4*)x)[(size_t)i * 2 + 1];
    ((us8*)out)[i] = cvt8(a, b);
  }
}

// ---------------- prepass: group_prob fp32 -> bf16 in S^T-fragment order ----------------
// lane (wid,hi,colb) needs g[b][q0+wid*16+colb][k0 + n*16 + hi*4 + rr] at slot n*4+rr
__global__ __launch_bounds__(256)
void cvt_gperm(const float* __restrict__ g, unsigned short* __restrict__ out)
{
  const int idx = blockIdx.x;                 // b*1024 + qt*32 + kt
  const int b = idx >> 10, rest = idx & 1023, qt = rest >> 5, kt = rest & 31;
  const int tid = threadIdx.x;
  const int colb = tid & 15, hi = (tid >> 4) & 3, wid = tid >> 6;
  const int q = qt * 64 + wid * 16 + colb;
  const float* row = g + ((size_t)b * Sc + q) * Sc + kt * 64 + hi * 4;
  unsigned short vals[16];
#pragma unroll
  for (int n = 0; n < 4; ++n) {
    float4 v = *(const float4*)(row + n * 16);
    vals[n * 4 + 0] = f2bf(v.x);
    vals[n * 4 + 1] = f2bf(v.y);
    vals[n * 4 + 2] = f2bf(v.z);
    vals[n * 4 + 3] = f2bf(v.w);
  }
  us8* o = (us8*)(out + (((size_t)idx * 256) + tid) * 16);
  o[0] = *(us8*)&vals[0];
  o[1] = *(us8*)&vals[8];
}

// ---------------- prepass: mask int32 -> bits (diag OR-folded) ----------------
__global__ __launch_bounds__(256)
void cvt_mask(const int* __restrict__ m, unsigned long long* __restrict__ out, int ngroups)
{
  const int lane = threadIdx.x & 63;
  int gid = (blockIdx.x * blockDim.x + threadIdx.x) >> 6;
  const int stride = (gridDim.x * blockDim.x) >> 6;
  for (; gid < ngroups; gid += stride) {
    const size_t base = (size_t)gid * 64;
    const int rem = (int)(base & ((size_t)Sc * Sc - 1));
    const int srow = rem >> 11;
    const int k = (rem & (Sc - 1)) + lane;
    const bool pred = (m[base + lane] != 0) || (k == srow);
    unsigned long long bal = __ballot(pred);
    if (lane == 0) out[gid] = bal;
  }
}

// C = A * W^T + bias.  A: [M,K] bf16, W: [N,K] fp32 (converted in staging).
// OUT_MODE 0: bf16 [M,N]; 1: bf16 per-batch transposed -> [b][n][s]; 2: fp32 [M,N].
template<int OUT_MODE>
__global__ __launch_bounds__(256)
void gemm_nt(const unsigned short* __restrict__ Ap, const float* __restrict__ Wp,
             const float* __restrict__ bias, void* __restrict__ Cp,
             int M, int N, int K)
{
  constexpr int KC = 32;
  __shared__ unsigned short As[64][KC + 8];
  __shared__ unsigned short Bs[64][KC + 8];
  const int tid = threadIdx.x;
  const int lane = tid & 63, wid = tid >> 6;
  const int m0 = blockIdx.x * 64, n0 = blockIdx.y * 64;

  f32x4 acc[4] = {{0,0,0,0},{0,0,0,0},{0,0,0,0},{0,0,0,0}};

  const int r = tid >> 2;
  const int c = (tid & 3) * 8;

  for (int k0 = 0; k0 < K; k0 += KC) {
    __syncthreads();
    *(us8*)&As[r][c] = *(const us8*)(Ap + (size_t)(m0 + r) * K + k0 + c);
    {
      const float* p = Wp + (size_t)(n0 + r) * K + k0 + c;
      float4 v0 = *(const float4*)p, v1 = *(const float4*)(p + 4);
      *(us8*)&Bs[r][c] = cvt8(v0, v1);
    }
    __syncthreads();
    bf16x8 af = *(const bf16x8*)&As[wid * 16 + (lane & 15)][(lane >> 4) * 8];
#pragma unroll
    for (int n = 0; n < 4; ++n) {
      bf16x8 bfv = *(const bf16x8*)&Bs[n * 16 + (lane & 15)][(lane >> 4) * 8];
      acc[n] = __builtin_amdgcn_mfma_f32_16x16x32_bf16(af, bfv, acc[n], 0, 0, 0);
    }
  }

  const int colb = lane & 15;
  const int rowb = (lane >> 4) * 4;
#pragma unroll
  for (int n = 0; n < 4; ++n) {
    const int gn = n0 + n * 16 + colb;
    const float bv = bias[gn];
#pragma unroll
    for (int rr = 0; rr < 4; ++rr) {
      const int gm = m0 + wid * 16 + rowb + rr;
      const float y = acc[n][rr] + bv;
      if (OUT_MODE == 0) {
        ((unsigned short*)Cp)[(size_t)gm * N + gn] = f2bf(y);
      } else if (OUT_MODE == 1) {
        const int bb = gm >> 11, ss = gm & (Sc - 1);
        ((unsigned short*)Cp)[((size_t)bb * N + gn) * Sc + ss] = f2bf(y);
      } else {
        ((float*)Cp)[(size_t)gm * N + gn] = y;
      }
    }
  }
}

// ---------------- split-K flash attention (swapped-operand S^T form) ----------------
// grid (B*H, S/64, SPLIT). Partials: Pacc[blk][d=64][q=64] (O^T), Pml[blk][2][64].
__global__ __launch_bounds__(256, 4)
void attn_split(const unsigned short* __restrict__ Qb,
                const unsigned short* __restrict__ Kb,
                const unsigned short* __restrict__ Vt,
                const unsigned short* __restrict__ Gp,
                const unsigned long long* __restrict__ Mb,
                float* __restrict__ Pacc,
                float* __restrict__ Pml)
{
  __shared__ unsigned short Ks[2][64][64];   // [k][dk], XOR-swizzled rows
  __shared__ unsigned short Vs[2][64][64];   // [dk][k], XOR-swizzled rows
  __shared__ unsigned short Ps[4][16][64];   // per-wave P [q][k], XOR-swizzled rows

  const int tid = threadIdx.x, lane = tid & 63, wid = tid >> 6;
  const int bh = blockIdx.x, b = bh >> 3, h = bh & 7;
  const int qt = blockIdx.y, q0 = qt * 64;
  const int sp = blockIdx.z;
  const int kt0 = sp * KT_PER;

  const int colb = lane & 15;
  const int hi = lane >> 4;
  const int rowb = hi * 4;
  const int c3s = (colb & 7) << 4;

  // Q fragment = B-operand of S^T mfma (lane holds Q[q=wid*16+colb][d=hi*8+j])
  bf16x8 qf[2];
  {
    const unsigned short* qp = Qb + ((size_t)(b * Sc + q0 + wid * 16 + colb) * Dc + h * DKc + hi * 8);
    qf[0] = *(const bf16x8*)qp;
    qf[1] = *(const bf16x8*)(qp + 32);
  }

  f32x4 acc[4] = {{0,0,0,0},{0,0,0,0},{0,0,0,0},{0,0,0,0}};   // acc[n][rr] = O^T[n*16+rowb+rr][q=wid*16+colb]
  float mrun = -1e30f, lrun = 0.f;                             // per q=colb scalars

  // async staging: linear LDS dest, inverse-swizzled global source
  auto stageKV = [&](int bufI, int kt) {
    const int k0 = kt * 64;
#pragma unroll
    for (int i = 0; i < 2; ++i) {
      const int obase = wid * 1024 + i * 4096;            // bytes within 8 KB tile
      const int row = (obase >> 7) + (lane >> 3);         // 0..63
      const int cb = ((lane & 7) * 16) ^ ((row & 7) << 4);
      const unsigned short* ksrc = Kb + (size_t)(b * Sc + k0 + row) * Dc + h * DKc + (cb >> 1);
      const unsigned short* vsrc = Vt + ((size_t)b * Dc + h * DKc + row) * Sc + k0 + (cb >> 1);
      __builtin_amdgcn_global_load_lds((g_void*)ksrc, (lds_void*)((char*)&Ks[bufI][0][0] + obase), 16, 0, 0);
      __builtin_amdgcn_global_load_lds((g_void*)vsrc, (lds_void*)((char*)&Vs[bufI][0][0] + obase), 16, 0, 0);
    }
  };

  const unsigned long long* mrow = Mb + ((size_t)(b * Sc) + q0 + wid * 16 + colb) * NKT;

  us8 gcur0, gcur1;
  unsigned long long mcur;
  auto loadGM = [&](int kt, us8& g0, us8& g1, unsigned long long& mm) {
    const us8* p = (const us8*)(Gp + (((size_t)(b * 1024 + qt * 32 + kt)) * 256 + tid) * 16);
    g0 = p[0]; g1 = p[1];
    mm = mrow[kt];
  };

  stageKV(0, kt0);
  loadGM(kt0, gcur0, gcur1, mcur);
  asm volatile("s_waitcnt vmcnt(0)" ::: "memory");
  __syncthreads();

  int buf = 0;
  char* psbase = (char*)&Ps[wid][0][0];

  for (int j = 0; j < KT_PER; ++j) {
    const int kt = kt0 + j;
    us8 gn0, gn1; unsigned long long mn_;
    if (j + 1 < KT_PER) {
      stageKV(buf ^ 1, kt + 1);          // async into other buffer
      loadGM(kt + 1, gn0, gn1, mn_);
    }

    // S^T = K Q^T : sf[n][rr] = S[q=colb][k = n*16 + hi*4 + rr]
    f32x4 sf[4] = {{0,0,0,0},{0,0,0,0},{0,0,0,0},{0,0,0,0}};
    char* ksb = (char*)&Ks[buf][0][0];
#pragma unroll
    for (int kk = 0; kk < 2; ++kk) {
#pragma unroll
      for (int n = 0; n < 4; ++n) {
        const int krow = n * 16 + colb;
        bf16x8 kf = *(const bf16x8*)(ksb + krow * 128 + ((kk * 64 + hi * 16) ^ ((krow & 7) << 4)));
        sf[n] = __builtin_amdgcn_mfma_f32_16x16x32_bf16(kf, qf[kk], sf[n], 0, 0, 0);
      }
    }

    // scale + mask (bits include diagonal); k-bit = n*16 + hi*4 + rr
    const unsigned long long msh = mcur >> (hi * 4);
#pragma unroll
    for (int n = 0; n < 4; ++n) {
#pragma unroll
      for (int rr = 0; rr < 4; ++rr) {
        const bool allowed = ((unsigned int)(msh >> (n * 16 + rr)) & 1u) != 0u;
        sf[n][rr] = allowed ? sf[n][rr] * 0.125f : -1e30f;
      }
    }

    // row max over this lane's 16 values, then combine the 4 hi-lanes
    float tm = sf[0][0];
#pragma unroll
    for (int n = 0; n < 4; ++n)
#pragma unroll
      for (int rr = 0; rr < 4; ++rr) tm = fmaxf(tm, sf[n][rr]);
    tm = fmaxf(tm, __shfl_xor(tm, 16));
    tm = fmaxf(tm, __shfl_xor(tm, 32));
    const float mnew = fmaxf(mrun, tm);
    const float alpha = __expf(mrun - mnew);
    mrun = mnew;

    // p = exp(s-m); pack p*g pairs; row sum
    float rsum = 0.f;
    unsigned int pw[8];
#pragma unroll
    for (int n = 0; n < 4; ++n) {
#pragma unroll
      for (int s2 = 0; s2 < 2; ++s2) {
        const int jv = n * 4 + s2 * 2;
        const float p0 = __expf(sf[n][s2 * 2]     - mnew);
        const float p1 = __expf(sf[n][s2 * 2 + 1] - mnew);
        rsum += p0 + p1;
        const float g0 = bf2f(jv < 8 ? gcur0.u[jv] : gcur1.u[jv - 8]);
        const float g1 = bf2f(jv + 1 < 8 ? gcur0.u[jv + 1] : gcur1.u[jv + 1 - 8]);
        const float q0v = p0 * g0, q1v = p1 * g1;
        asm("v_cvt_pk_bf16_f32 %0, %1, %2" : "=v"(pw[n * 2 + s2]) : "v"(q0v), "v"(q1v));
      }
    }
    rsum += __shfl_xor(rsum, 16);
    rsum += __shfl_xor(rsum, 32);
    lrun = lrun * alpha + rsum;

    // store P [q=colb][k] as 4x ds_write_b64 (pairs are k-contiguous)
#pragma unroll
    for (int n = 0; n < 4; ++n) {
      const unsigned long long w64 = ((unsigned long long)pw[n * 2 + 1] << 32) | pw[n * 2];
      *(unsigned long long*)(psbase + colb * 128 + ((n * 32 + hi * 8) ^ c3s)) = w64;
    }

    // acc = acc*alpha + V^T P^T  (O^T layout; Ps wave-private)
#pragma unroll
    for (int n = 0; n < 4; ++n)
#pragma unroll
      for (int rr = 0; rr < 4; ++rr) acc[n][rr] *= alpha;
    char* vsb = (char*)&Vs[buf][0][0];
#pragma unroll
    for (int kk = 0; kk < 2; ++kk) {
      bf16x8 pf = *(const bf16x8*)(psbase + colb * 128 + ((kk * 64 + hi * 16) ^ c3s));
#pragma unroll
      for (int n = 0; n < 4; ++n) {
        const int vrow = n * 16 + colb;
        bf16x8 vf = *(const bf16x8*)(vsb + vrow * 128 + ((kk * 64 + hi * 16) ^ ((vrow & 7) << 4)));
        acc[n] = __builtin_amdgcn_mfma_f32_16x16x32_bf16(vf, pf, acc[n], 0, 0, 0);
      }
    }

    asm volatile("s_waitcnt vmcnt(0)" ::: "memory");
    __syncthreads();
    buf ^= 1;
    if (j + 1 < KT_PER) { gcur0 = gn0; gcur1 = gn1; mcur = mn_; }
  }

  // write partials (O^T layout: [d][q])
  const size_t blin = ((size_t)bh * 32 + qt) * SPLIT + sp;
  float* pa = Pacc + blin * 4096;
#pragma unroll
  for (int n = 0; n < 4; ++n)
#pragma unroll
    for (int rr = 0; rr < 4; ++rr)
      pa[(size_t)(n * 16 + rowb + rr) * 64 + wid * 16 + colb] = acc[n][rr];
  if (hi == 0) {
    float* pm = Pml + blin * 128;
    pm[wid * 16 + colb] = mrun;
    pm[64 + wid * 16 + colb] = lrun;
  }
}

// ---------------- recombine split partials -> bf16 X ----------------
__global__ __launch_bounds__(256)
void attn_reduce(const float* __restrict__ Pacc, const float* __restrict__ Pml,
                 unsigned short* __restrict__ Xb)
{
  const int gidx = blockIdx.x;      // bh*32 + qt
  const int bh = gidx >> 5, qt = gidx & 31;
  const int b = bh >> 3, h = bh & 7;
  const int tid = threadIdx.x;
  const int qi = tid & 63;
  const int d0 = (tid >> 6) * 16;
  const size_t pb = (size_t)gidx * SPLIT;

  float m[SPLIT], l[SPLIT];
  float mstar = -3.0e38f;
#pragma unroll
  for (int s = 0; s < SPLIT; ++s) {
    m[s] = Pml[(pb + s) * 128 + qi];
    l[s] = Pml[(pb + s) * 128 + 64 + qi];
    mstar = fmaxf(mstar, m[s]);
  }
  float w[SPLIT], denom = 0.f;
#pragma unroll
  for (int s = 0; s < SPLIT; ++s) { w[s] = __expf(m[s] - mstar); denom += w[s] * l[s]; }
  const float inv = 1.0f / denom;

  unsigned short vals[16];
#pragma unroll
  for (int j = 0; j < 16; ++j) {
    float a = 0.f;
#pragma unroll
    for (int s = 0; s < SPLIT; ++s)
      a += w[s] * Pacc[(pb + s) * 4096 + (size_t)(d0 + j) * 64 + qi];
    vals[j] = f2bf(a * inv);
  }
  unsigned short* xp = Xb + ((size_t)(b * Sc) + qt * 64 + qi) * Dc + h * DKc + d0;
  *(us8*)xp = *(us8*)&vals[0];
  *(us8*)(xp + 8) = *(us8*)&vals[8];
}

extern "C" void kernel_launch(void* const* d_in, const int* in_sizes, int n_in,
                              void* d_out, int out_size, void* d_ws, size_t ws_size,
                              hipStream_t stream)
{
  const float* query = (const float*)d_in[0];
  const float* key_  = (const float*)d_in[1];
  const float* value = (const float*)d_in[2];
  const float* gprob = (const float*)d_in[3];
  const int*   mask  = (const int*)d_in[4];
  const float* Wq = (const float*)d_in[5];
  const float* bq = (const float*)d_in[6];
  const float* Wk = (const float*)d_in[7];
  const float* bk = (const float*)d_in[8];
  const float* Wv = (const float*)d_in[9];
  const float* bv = (const float*)d_in[10];
  const float* Wo = (const float*)d_in[11];
  const float* bo = (const float*)d_in[12];
  float* out = (float*)d_out;

  const size_t elems = (size_t)Bc * Sc * Dc;     // 2 Mi
  const size_t gelems = (size_t)Bc * Sc * Sc;    // 8 Mi

  char* base = (char*)d_ws;
  unsigned short* Qb = (unsigned short*)(base);                    // 4 MB
  unsigned short* Kb = Qb + elems;                                 // 4 MB
  unsigned short* Vt = Kb + elems;                                 // 4 MB
  unsigned short* Xb = Vt + elems;                                 // 4 MB
  unsigned short* Gp = Xb + elems;                                 // 16 MB
  unsigned long long* Mbits = (unsigned long long*)(Gp + gelems);  // 1 MB
  char* shared_region = (char*)(Mbits + gelems / 64);
  unsigned short* Ain = (unsigned short*)shared_region;            // 4 MB
  unsigned short* Bin = Ain + elems;                               // 4 MB
  unsigned short* Cin = Bin + elems;                               // 4 MB
  float* Pacc = (float*)shared_region;                             // 16.8 MB
  float* Pml  = Pacc + (size_t)(Bc * Hc) * 32 * SPLIT * 4096;      // 0.5 MB

  // prepasses
  hipLaunchKernelGGL(cvt_bf16, dim3(1024), dim3(256), 0, stream, query, Ain, (int)(elems / 8));
  hipLaunchKernelGGL(cvt_bf16, dim3(1024), dim3(256), 0, stream, key_,  Bin, (int)(elems / 8));
  hipLaunchKernelGGL(cvt_bf16, dim3(1024), dim3(256), 0, stream, value, Cin, (int)(elems / 8));
  hipLaunchKernelGGL(cvt_gperm, dim3(2048), dim3(256), 0, stream, gprob, Gp);
  hipLaunchKernelGGL(cvt_mask, dim3(2048), dim3(256), 0, stream, mask, Mbits, (int)(gelems / 64));

  const int M = Bc * Sc, N = Dc, K = Dc;
  dim3 gg(M / 64, N / 64), blk(256);
  hipLaunchKernelGGL((gemm_nt<0>), gg, blk, 0, stream, Ain, Wq, bq, (void*)Qb, M, N, K);
  hipLaunchKernelGGL((gemm_nt<0>), gg, blk, 0, stream, Bin, Wk, bk, (void*)Kb, M, N, K);
  hipLaunchKernelGGL((gemm_nt<1>), gg, blk, 0, stream, Cin, Wv, bv, (void*)Vt, M, N, K);

  dim3 ga(Bc * Hc, Sc / 64, SPLIT);
  hipLaunchKernelGGL(attn_split, ga, blk, 0, stream, Qb, Kb, Vt, Gp, Mbits, Pacc, Pml);
  hipLaunchKernelGGL(attn_reduce, dim3(Bc * Hc * 32), blk, 0, stream, Pacc, Pml, Xb);

  hipLaunchKernelGGL((gemm_nt<2>), gg, blk, 0, stream, Xb, Wo, bo, (void*)out, M, N, K);
}

// Round 5
// 112.123 us; speedup vs baseline: 1.9830x; 1.2516x over previous
//
#include <hip/hip_runtime.h>
#include <hip/hip_bf16.h>
#include <cstdint>
#include <cstddef>

typedef __attribute__((ext_vector_type(8))) short bf16x8;
typedef __attribute__((ext_vector_type(4))) float f32x4;
typedef __attribute__((address_space(3))) void lds_void;
typedef const __attribute__((address_space(1))) void g_void;

constexpr int Bc = 2, Sc = 2048, Dc = 512, Hc = 8, DKc = 64;
constexpr int SPLIT = 2;
constexpr int NKT = Sc / 64;           // 32 k-tiles total
constexpr int KT_PER = NKT / SPLIT;    // 16 per block

struct alignas(16) us8 { unsigned short u[8]; };
struct alignas(8) us4 { unsigned short u[4]; };

__device__ __forceinline__ unsigned short f2bf(float x) {
  union { float f; unsigned int u; } v; v.f = x;
  unsigned int r = (v.u + 0x7FFFu + ((v.u >> 16) & 1u)) >> 16;
  return (unsigned short)r;
}

__device__ __forceinline__ float bf2f(unsigned short u) {
  union { unsigned int u; float f; } v; v.u = ((unsigned int)u) << 16;
  return v.f;
}

__device__ __forceinline__ us8 cvt8(float4 a, float4 b) {
  us8 o;
  o.u[0] = f2bf(a.x); o.u[1] = f2bf(a.y); o.u[2] = f2bf(a.z); o.u[3] = f2bf(a.w);
  o.u[4] = f2bf(b.x); o.u[5] = f2bf(b.y); o.u[6] = f2bf(b.z); o.u[7] = f2bf(b.w);
  return o;
}

// ---------------- prepass: 7 fp32->bf16 conversions in one launch ----------------
struct CArgs { const float* src[7]; unsigned short* dst[7]; int n8[7]; };

__global__ __launch_bounds__(256)
void cvt_multi(CArgs a)
{
  const int y = blockIdx.y;
  const float* s = a.src[y];
  unsigned short* d = a.dst[y];
  const int n8 = a.n8[y];
  int i = blockIdx.x * blockDim.x + threadIdx.x;
  const int stride = gridDim.x * blockDim.x;
  for (; i < n8; i += stride) {
    float4 va = ((const float4*)s)[(size_t)i * 2];
    float4 vb = ((const float4*)s)[(size_t)i * 2 + 1];
    ((us8*)d)[i] = cvt8(va, vb);
  }
}

// ---------------- prepass: group_prob fp32 -> bf16 in S^T-fragment order ----------------
__global__ __launch_bounds__(256)
void cvt_gperm(const float* __restrict__ g, unsigned short* __restrict__ out)
{
  const int idx = blockIdx.x;                 // b*1024 + qt*32 + kt
  const int b = idx >> 10, rest = idx & 1023, qt = rest >> 5, kt = rest & 31;
  const int tid = threadIdx.x;
  const int colb = tid & 15, hi = (tid >> 4) & 3, wid = tid >> 6;
  const int q = qt * 64 + wid * 16 + colb;
  const float* row = g + ((size_t)b * Sc + q) * Sc + kt * 64 + hi * 4;
  unsigned short vals[16];
#pragma unroll
  for (int n = 0; n < 4; ++n) {
    float4 v = *(const float4*)(row + n * 16);
    vals[n * 4 + 0] = f2bf(v.x);
    vals[n * 4 + 1] = f2bf(v.y);
    vals[n * 4 + 2] = f2bf(v.z);
    vals[n * 4 + 3] = f2bf(v.w);
  }
  us8* o = (us8*)(out + (((size_t)idx * 256) + tid) * 16);
  o[0] = *(us8*)&vals[0];
  o[1] = *(us8*)&vals[8];
}

// ---------------- prepass: mask int32 -> bits (diag OR-folded) ----------------
__global__ __launch_bounds__(256)
void cvt_mask(const int* __restrict__ m, unsigned long long* __restrict__ out, int ngroups)
{
  const int lane = threadIdx.x & 63;
  int gid = (blockIdx.x * blockDim.x + threadIdx.x) >> 6;
  const int stride = (gridDim.x * blockDim.x) >> 6;
  for (; gid < ngroups; gid += stride) {
    const size_t base = (size_t)gid * 64;
    const int rem = (int)(base & ((size_t)Sc * Sc - 1));
    const int srow = rem >> 11;
    const int k = (rem & (Sc - 1)) + lane;
    const bool pred = (m[base + lane] != 0) || (k == srow);
    unsigned long long bal = __ballot(pred);
    if (lane == 0) out[gid] = bal;
  }
}

// ---------------- 128x128-tile bf16 NT GEMM (m97 structure) ----------------
// C = A * W^T + bias.  A,W bf16 (pre-converted).  M=4096, N=512, K=512.
// mode 0: bf16 [M,N]; 1: bf16 per-batch transposed [b][n][s]; 2: fp32 [M,N].
struct GArgs {
  const unsigned short* A[3];
  const unsigned short* W[3];
  const float* bias[3];
  void* C[3];
  int mode[3];
};

__global__ __launch_bounds__(256)
void gemm128(GArgs ga)
{
  __shared__ unsigned short As[128][64];   // XOR-swizzled rows (128 B, 8 slots)
  __shared__ unsigned short Bs[128][64];

  constexpr int K = 512, N = 512;
  const int z = blockIdx.z;
  const unsigned short* Ap = ga.A[z];
  const unsigned short* Wp = ga.W[z];
  const float* bias = ga.bias[z];
  const int mode = ga.mode[z];

  const int tid = threadIdx.x, lane = tid & 63, w = tid >> 6;
  const int m0 = blockIdx.x * 128, n0 = blockIdx.y * 128;
  const int wm = w >> 1, wn = w & 1;
  const int colb = lane & 15, hi = lane >> 4, rowb = hi * 4;
  const int swz = (colb & 7) << 4;          // fragment-read XOR (row&7 == colb&7)

  f32x4 acc[4][4];
#pragma unroll
  for (int i = 0; i < 4; ++i)
#pragma unroll
    for (int j = 0; j < 4; ++j) acc[i][j] = (f32x4){0.f, 0.f, 0.f, 0.f};

  const int lrow8 = lane >> 3;                          // staging row&7
  const int cb = ((lane & 7) * 16) ^ (lrow8 << 4);      // pre-swizzled src col-bytes

  for (int k0 = 0; k0 < K; k0 += 64) {
    if (k0) __syncthreads();
#pragma unroll
    for (int i = 0; i < 4; ++i) {
      const int obase = w * 1024 + i * 4096;            // wave-uniform dest (lane*16 implicit)
      const int row = w * 8 + i * 32 + lrow8;
      const unsigned short* asrc = Ap + (size_t)(m0 + row) * K + k0 + (cb >> 1);
      const unsigned short* bsrc = Wp + (size_t)(n0 + row) * K + k0 + (cb >> 1);
      __builtin_amdgcn_global_load_lds((g_void*)asrc, (lds_void*)((char*)&As[0][0] + obase), 16, 0, 0);
      __builtin_amdgcn_global_load_lds((g_void*)bsrc, (lds_void*)((char*)&Bs[0][0] + obase), 16, 0, 0);
    }
    asm volatile("s_waitcnt vmcnt(0)" ::: "memory");
    __syncthreads();

    char* ab = (char*)&As[0][0];
    char* bb = (char*)&Bs[0][0];
#pragma unroll
    for (int kk = 0; kk < 2; ++kk) {
      bf16x8 af[4], bfr[4];
#pragma unroll
      for (int mf = 0; mf < 4; ++mf) {
        const int ar = wm * 64 + mf * 16 + colb;
        af[mf] = *(const bf16x8*)(ab + ar * 128 + ((kk * 64 + hi * 16) ^ swz));
      }
#pragma unroll
      for (int nf = 0; nf < 4; ++nf) {
        const int br = wn * 64 + nf * 16 + colb;
        bfr[nf] = *(const bf16x8*)(bb + br * 128 + ((kk * 64 + hi * 16) ^ swz));
      }
#pragma unroll
      for (int mf = 0; mf < 4; ++mf)
#pragma unroll
        for (int nf = 0; nf < 4; ++nf)
          acc[mf][nf] = __builtin_amdgcn_mfma_f32_16x16x32_bf16(af[mf], bfr[nf], acc[mf][nf], 0, 0, 0);
    }
  }

  // epilogue
#pragma unroll
  for (int nf = 0; nf < 4; ++nf) {
    const int gn = n0 + wn * 64 + nf * 16 + colb;
    const float bv = bias[gn];
    if (mode == 1) {
      unsigned short* Cp = (unsigned short*)ga.C[z];
#pragma unroll
      for (int mf = 0; mf < 4; ++mf) {
        const int gm = m0 + wm * 64 + mf * 16 + rowb;
        const int bb_ = gm >> 11, ss = gm & (Sc - 1);
        us4 vv;
#pragma unroll
        for (int rr = 0; rr < 4; ++rr) vv.u[rr] = f2bf(acc[mf][nf][rr] + bv);
        *(us4*)(Cp + ((size_t)bb_ * N + gn) * Sc + ss) = vv;
      }
    } else if (mode == 0) {
      unsigned short* Cp = (unsigned short*)ga.C[z];
#pragma unroll
      for (int mf = 0; mf < 4; ++mf)
#pragma unroll
        for (int rr = 0; rr < 4; ++rr) {
          const int gm = m0 + wm * 64 + mf * 16 + rowb + rr;
          Cp[(size_t)gm * N + gn] = f2bf(acc[mf][nf][rr] + bv);
        }
    } else {
      float* Cp = (float*)ga.C[z];
#pragma unroll
      for (int mf = 0; mf < 4; ++mf)
#pragma unroll
        for (int rr = 0; rr < 4; ++rr) {
          const int gm = m0 + wm * 64 + mf * 16 + rowb + rr;
          Cp[(size_t)gm * N + gn] = acc[mf][nf][rr] + bv;
        }
    }
  }
}

// ---------------- split-K flash attention (swapped-operand S^T form) ----------------
// grid (B*H, S/64, SPLIT). Partials: Pacc[blk][d=64][q=64] (O^T), Pml[blk][2][64].
__global__ __launch_bounds__(256, 4)
void attn_split(const unsigned short* __restrict__ Qb,
                const unsigned short* __restrict__ Kb,
                const unsigned short* __restrict__ Vt,
                const unsigned short* __restrict__ Gp,
                const unsigned long long* __restrict__ Mb,
                float* __restrict__ Pacc,
                float* __restrict__ Pml)
{
  __shared__ unsigned short Ks[2][64][64];   // [k][dk], XOR-swizzled rows
  __shared__ unsigned short Vs[2][64][64];   // [dk][k], XOR-swizzled rows
  __shared__ unsigned short Ps[4][16][64];   // per-wave P [q][k], XOR-swizzled rows

  const int tid = threadIdx.x, lane = tid & 63, wid = tid >> 6;
  const int bh = blockIdx.x, b = bh >> 3, h = bh & 7;
  const int qt = blockIdx.y, q0 = qt * 64;
  const int sp = blockIdx.z;
  const int kt0 = sp * KT_PER;

  const int colb = lane & 15;
  const int hi = lane >> 4;
  const int rowb = hi * 4;
  const int c3s = (colb & 7) << 4;

  // Q fragment = B-operand of S^T mfma (lane holds Q[q=wid*16+colb][d=hi*8+j])
  bf16x8 qf[2];
  {
    const unsigned short* qp = Qb + ((size_t)(b * Sc + q0 + wid * 16 + colb) * Dc + h * DKc + hi * 8);
    qf[0] = *(const bf16x8*)qp;
    qf[1] = *(const bf16x8*)(qp + 32);
  }

  f32x4 acc[4] = {{0,0,0,0},{0,0,0,0},{0,0,0,0},{0,0,0,0}};   // acc[n][rr] = O^T[n*16+rowb+rr][q=wid*16+colb]
  float mrun = -1e30f, lrun = 0.f;                             // per q=colb scalars

  // async staging: linear LDS dest, inverse-swizzled global source
  auto stageKV = [&](int bufI, int kt) {
    const int k0 = kt * 64;
#pragma unroll
    for (int i = 0; i < 2; ++i) {
      const int obase = wid * 1024 + i * 4096;            // bytes within 8 KB tile
      const int row = (obase >> 7) + (lane >> 3);         // 0..63
      const int cb = ((lane & 7) * 16) ^ ((row & 7) << 4);
      const unsigned short* ksrc = Kb + (size_t)(b * Sc + k0 + row) * Dc + h * DKc + (cb >> 1);
      const unsigned short* vsrc = Vt + ((size_t)b * Dc + h * DKc + row) * Sc + k0 + (cb >> 1);
      __builtin_amdgcn_global_load_lds((g_void*)ksrc, (lds_void*)((char*)&Ks[bufI][0][0] + obase), 16, 0, 0);
      __builtin_amdgcn_global_load_lds((g_void*)vsrc, (lds_void*)((char*)&Vs[bufI][0][0] + obase), 16, 0, 0);
    }
  };

  const unsigned long long* mrow = Mb + ((size_t)(b * Sc) + q0 + wid * 16 + colb) * NKT;

  us8 gcur0, gcur1;
  unsigned long long mcur;
  auto loadGM = [&](int kt, us8& g0, us8& g1, unsigned long long& mm) {
    const us8* p = (const us8*)(Gp + (((size_t)(b * 1024 + qt * 32 + kt)) * 256 + tid) * 16);
    g0 = p[0]; g1 = p[1];
    mm = mrow[kt];
  };

  stageKV(0, kt0);
  loadGM(kt0, gcur0, gcur1, mcur);
  asm volatile("s_waitcnt vmcnt(0)" ::: "memory");
  __syncthreads();

  int buf = 0;
  char* psbase = (char*)&Ps[wid][0][0];

  for (int j = 0; j < KT_PER; ++j) {
    const int kt = kt0 + j;
    us8 gn0, gn1; unsigned long long mn_;
    if (j + 1 < KT_PER) {
      stageKV(buf ^ 1, kt + 1);          // async into other buffer
      loadGM(kt + 1, gn0, gn1, mn_);
    }

    // S^T = K Q^T : sf[n][rr] = S[q=colb][k = n*16 + hi*4 + rr]
    f32x4 sf[4] = {{0,0,0,0},{0,0,0,0},{0,0,0,0},{0,0,0,0}};
    char* ksb = (char*)&Ks[buf][0][0];
#pragma unroll
    for (int kk = 0; kk < 2; ++kk) {
#pragma unroll
      for (int n = 0; n < 4; ++n) {
        const int krow = n * 16 + colb;
        bf16x8 kf = *(const bf16x8*)(ksb + krow * 128 + ((kk * 64 + hi * 16) ^ ((krow & 7) << 4)));
        sf[n] = __builtin_amdgcn_mfma_f32_16x16x32_bf16(kf, qf[kk], sf[n], 0, 0, 0);
      }
    }

    // scale + mask (bits include diagonal); k-bit = n*16 + hi*4 + rr
    const unsigned long long msh = mcur >> (hi * 4);
#pragma unroll
    for (int n = 0; n < 4; ++n) {
#pragma unroll
      for (int rr = 0; rr < 4; ++rr) {
        const bool allowed = ((unsigned int)(msh >> (n * 16 + rr)) & 1u) != 0u;
        sf[n][rr] = allowed ? sf[n][rr] * 0.125f : -1e30f;
      }
    }

    // row max over this lane's 16 values, then combine the 4 hi-lanes
    float tm = sf[0][0];
#pragma unroll
    for (int n = 0; n < 4; ++n)
#pragma unroll
      for (int rr = 0; rr < 4; ++rr) tm = fmaxf(tm, sf[n][rr]);
    tm = fmaxf(tm, __shfl_xor(tm, 16));
    tm = fmaxf(tm, __shfl_xor(tm, 32));
    const float mnew = fmaxf(mrun, tm);
    const float alpha = __expf(mrun - mnew);
    mrun = mnew;

    // p = exp(s-m); pack p*g pairs; row sum
    float rsum = 0.f;
    unsigned int pw[8];
#pragma unroll
    for (int n = 0; n < 4; ++n) {
#pragma unroll
      for (int s2 = 0; s2 < 2; ++s2) {
        const int jv = n * 4 + s2 * 2;
        const float p0 = __expf(sf[n][s2 * 2]     - mnew);
        const float p1 = __expf(sf[n][s2 * 2 + 1] - mnew);
        rsum += p0 + p1;
        const float g0 = bf2f(jv < 8 ? gcur0.u[jv] : gcur1.u[jv - 8]);
        const float g1 = bf2f(jv + 1 < 8 ? gcur0.u[jv + 1] : gcur1.u[jv + 1 - 8]);
        const float q0v = p0 * g0, q1v = p1 * g1;
        asm("v_cvt_pk_bf16_f32 %0, %1, %2" : "=v"(pw[n * 2 + s2]) : "v"(q0v), "v"(q1v));
      }
    }
    rsum += __shfl_xor(rsum, 16);
    rsum += __shfl_xor(rsum, 32);
    lrun = lrun * alpha + rsum;

    // store P [q=colb][k] as 4x ds_write_b64 (pairs are k-contiguous)
#pragma unroll
    for (int n = 0; n < 4; ++n) {
      const unsigned long long w64 = ((unsigned long long)pw[n * 2 + 1] << 32) | pw[n * 2];
      *(unsigned long long*)(psbase + colb * 128 + ((n * 32 + hi * 8) ^ c3s)) = w64;
    }

    // acc = acc*alpha + V^T P^T  (O^T layout; Ps wave-private)
#pragma unroll
    for (int n = 0; n < 4; ++n)
#pragma unroll
      for (int rr = 0; rr < 4; ++rr) acc[n][rr] *= alpha;
    char* vsb = (char*)&Vs[buf][0][0];
#pragma unroll
    for (int kk = 0; kk < 2; ++kk) {
      bf16x8 pf = *(const bf16x8*)(psbase + colb * 128 + ((kk * 64 + hi * 16) ^ c3s));
#pragma unroll
      for (int n = 0; n < 4; ++n) {
        const int vrow = n * 16 + colb;
        bf16x8 vf = *(const bf16x8*)(vsb + vrow * 128 + ((kk * 64 + hi * 16) ^ ((vrow & 7) << 4)));
        acc[n] = __builtin_amdgcn_mfma_f32_16x16x32_bf16(vf, pf, acc[n], 0, 0, 0);
      }
    }

    asm volatile("s_waitcnt vmcnt(0)" ::: "memory");
    __syncthreads();
    buf ^= 1;
    if (j + 1 < KT_PER) { gcur0 = gn0; gcur1 = gn1; mcur = mn_; }
  }

  // write partials (O^T layout: [d][q])
  const size_t blin = ((size_t)bh * 32 + qt) * SPLIT + sp;
  float* pa = Pacc + blin * 4096;
#pragma unroll
  for (int n = 0; n < 4; ++n)
#pragma unroll
    for (int rr = 0; rr < 4; ++rr)
      pa[(size_t)(n * 16 + rowb + rr) * 64 + wid * 16 + colb] = acc[n][rr];
  if (hi == 0) {
    float* pm = Pml + blin * 128;
    pm[wid * 16 + colb] = mrun;
    pm[64 + wid * 16 + colb] = lrun;
  }
}

// ---------------- recombine split partials -> bf16 X ----------------
__global__ __launch_bounds__(256)
void attn_reduce(const float* __restrict__ Pacc, const float* __restrict__ Pml,
                 unsigned short* __restrict__ Xb)
{
  const int gidx = blockIdx.x;      // bh*32 + qt
  const int bh = gidx >> 5, qt = gidx & 31;
  const int b = bh >> 3, h = bh & 7;
  const int tid = threadIdx.x;
  const int qi = tid & 63;
  const int d0 = (tid >> 6) * 16;
  const size_t pb = (size_t)gidx * SPLIT;

  float m[SPLIT], l[SPLIT];
  float mstar = -3.0e38f;
#pragma unroll
  for (int s = 0; s < SPLIT; ++s) {
    m[s] = Pml[(pb + s) * 128 + qi];
    l[s] = Pml[(pb + s) * 128 + 64 + qi];
    mstar = fmaxf(mstar, m[s]);
  }
  float w[SPLIT], denom = 0.f;
#pragma unroll
  for (int s = 0; s < SPLIT; ++s) { w[s] = __expf(m[s] - mstar); denom += w[s] * l[s]; }
  const float inv = 1.0f / denom;

  unsigned short vals[16];
#pragma unroll
  for (int j = 0; j < 16; ++j) {
    float a = 0.f;
#pragma unroll
    for (int s = 0; s < SPLIT; ++s)
      a += w[s] * Pacc[(pb + s) * 4096 + (size_t)(d0 + j) * 64 + qi];
    vals[j] = f2bf(a * inv);
  }
  unsigned short* xp = Xb + ((size_t)(b * Sc) + qt * 64 + qi) * Dc + h * DKc + d0;
  *(us8*)xp = *(us8*)&vals[0];
  *(us8*)(xp + 8) = *(us8*)&vals[8];
}

extern "C" void kernel_launch(void* const* d_in, const int* in_sizes, int n_in,
                              void* d_out, int out_size, void* d_ws, size_t ws_size,
                              hipStream_t stream)
{
  const float* query = (const float*)d_in[0];
  const float* key_  = (const float*)d_in[1];
  const float* value = (const float*)d_in[2];
  const float* gprob = (const float*)d_in[3];
  const int*   mask  = (const int*)d_in[4];
  const float* Wq = (const float*)d_in[5];
  const float* bq = (const float*)d_in[6];
  const float* Wk = (const float*)d_in[7];
  const float* bk = (const float*)d_in[8];
  const float* Wv = (const float*)d_in[9];
  const float* bv = (const float*)d_in[10];
  const float* Wo = (const float*)d_in[11];
  const float* bo = (const float*)d_in[12];
  float* out = (float*)d_out;

  const size_t elems = (size_t)Bc * Sc * Dc;     // 2 Mi
  const size_t gelems = (size_t)Bc * Sc * Sc;    // 8 Mi
  const size_t welems = (size_t)Dc * Dc;         // 256 Ki

  char* base = (char*)d_ws;
  unsigned short* Qb = (unsigned short*)(base);                    // 4 MB
  unsigned short* Kb = Qb + elems;                                 // 4 MB
  unsigned short* Vt = Kb + elems;                                 // 4 MB
  unsigned short* Xb = Vt + elems;                                 // 4 MB
  unsigned short* Gp = Xb + elems;                                 // 16 MB
  unsigned long long* Mbits = (unsigned long long*)(Gp + gelems);  // 1 MB
  char* shared_region = (char*)(Mbits + gelems / 64);
  // shared region: first bf16 copies of q/k/v inputs, later split partials
  unsigned short* Ain = (unsigned short*)shared_region;            // 4 MB
  unsigned short* Bin = Ain + elems;                               // 4 MB
  unsigned short* Cin = Bin + elems;                               // 4 MB
  float* Pacc = (float*)shared_region;                             // 16.8 MB
  float* Pml  = Pacc + (size_t)(Bc * Hc) * 32 * SPLIT * 4096;      // 0.5 MB
  // weights (bf16) live past the shared region's max extent (17.3 MB)
  unsigned short* Wqb = (unsigned short*)(shared_region + (18u << 20));
  unsigned short* Wkb = Wqb + welems;
  unsigned short* Wvb = Wkb + welems;
  unsigned short* Wob = Wvb + welems;

  // prepasses
  CArgs ca;
  ca.src[0] = query; ca.dst[0] = Ain; ca.n8[0] = (int)(elems / 8);
  ca.src[1] = key_;  ca.dst[1] = Bin; ca.n8[1] = (int)(elems / 8);
  ca.src[2] = value; ca.dst[2] = Cin; ca.n8[2] = (int)(elems / 8);
  ca.src[3] = Wq;    ca.dst[3] = Wqb; ca.n8[3] = (int)(welems / 8);
  ca.src[4] = Wk;    ca.dst[4] = Wkb; ca.n8[4] = (int)(welems / 8);
  ca.src[5] = Wv;    ca.dst[5] = Wvb; ca.n8[5] = (int)(welems / 8);
  ca.src[6] = Wo;    ca.dst[6] = Wob; ca.n8[6] = (int)(welems / 8);
  hipLaunchKernelGGL(cvt_multi, dim3(128, 7), dim3(256), 0, stream, ca);
  hipLaunchKernelGGL(cvt_gperm, dim3(2048), dim3(256), 0, stream, gprob, Gp);
  hipLaunchKernelGGL(cvt_mask, dim3(2048), dim3(256), 0, stream, mask, Mbits, (int)(gelems / 64));

  // fused Q/K/V projections
  GArgs gq;
  gq.A[0] = Ain; gq.W[0] = Wqb; gq.bias[0] = bq; gq.C[0] = (void*)Qb; gq.mode[0] = 0;
  gq.A[1] = Bin; gq.W[1] = Wkb; gq.bias[1] = bk; gq.C[1] = (void*)Kb; gq.mode[1] = 0;
  gq.A[2] = Cin; gq.W[2] = Wvb; gq.bias[2] = bv; gq.C[2] = (void*)Vt; gq.mode[2] = 1;
  hipLaunchKernelGGL(gemm128, dim3(32, 4, 3), dim3(256), 0, stream, gq);

  dim3 ga(Bc * Hc, Sc / 64, SPLIT);
  hipLaunchKernelGGL(attn_split, ga, dim3(256), 0, stream, Qb, Kb, Vt, Gp, Mbits, Pacc, Pml);
  hipLaunchKernelGGL(attn_reduce, dim3(Bc * Hc * 32), dim3(256), 0, stream, Pacc, Pml, Xb);

  // output projection
  GArgs go;
  go.A[0] = Xb; go.W[0] = Wob; go.bias[0] = bo; go.C[0] = (void*)out; go.mode[0] = 2;
  go.A[1] = Xb; go.W[1] = Wob; go.bias[1] = bo; go.C[1] = (void*)out; go.mode[1] = 2;
  go.A[2] = Xb; go.W[2] = Wob; go.bias[2] = bo; go.C[2] = (void*)out; go.mode[2] = 2;
  hipLaunchKernelGGL(gemm128, dim3(32, 4, 1), dim3(256), 0, stream, go);
}

// Round 6
// 110.723 us; speedup vs baseline: 2.0080x; 1.0126x over previous
//
#include <hip/hip_runtime.h>
#include <hip/hip_bf16.h>
#include <cstdint>
#include <cstddef>

typedef __attribute__((ext_vector_type(8))) short bf16x8;
typedef __attribute__((ext_vector_type(4))) float f32x4;
typedef __attribute__((address_space(3))) void lds_void;
typedef const __attribute__((address_space(1))) void g_void;

constexpr int Bc = 2, Sc = 2048, Dc = 512, Hc = 8, DKc = 64;
constexpr int SPLIT = 2;
constexpr int NKT = Sc / 64;           // 32 k-tiles total
constexpr int KT_PER = NKT / SPLIT;    // 16 per block
constexpr float CSC = 0.18033688011112042f;  // 0.125 * log2(e): score scale folded into exp2 domain

struct alignas(16) us8 { unsigned short u[8]; };
struct alignas(8) us4 { unsigned short u[4]; };

__device__ __forceinline__ unsigned short f2bf(float x) {
  union { float f; unsigned int u; } v; v.f = x;
  unsigned int r = (v.u + 0x7FFFu + ((v.u >> 16) & 1u)) >> 16;
  return (unsigned short)r;
}

__device__ __forceinline__ us8 cvt8(float4 a, float4 b) {
  us8 o;
  o.u[0] = f2bf(a.x); o.u[1] = f2bf(a.y); o.u[2] = f2bf(a.z); o.u[3] = f2bf(a.w);
  o.u[4] = f2bf(b.x); o.u[5] = f2bf(b.y); o.u[6] = f2bf(b.z); o.u[7] = f2bf(b.w);
  return o;
}

// ---------------- prepass: 7 fp32->bf16 conversions in one launch ----------------
struct CArgs { const float* src[7]; unsigned short* dst[7]; int n8[7]; };

__global__ __launch_bounds__(256)
void cvt_multi(CArgs a)
{
  const int y = blockIdx.y;
  const float* s = a.src[y];
  unsigned short* d = a.dst[y];
  const int n8 = a.n8[y];
  int i = blockIdx.x * blockDim.x + threadIdx.x;
  const int stride = gridDim.x * blockDim.x;
  for (; i < n8; i += stride) {
    float4 va = ((const float4*)s)[(size_t)i * 2];
    float4 vb = ((const float4*)s)[(size_t)i * 2 + 1];
    ((us8*)d)[i] = cvt8(va, vb);
  }
}

// ---------------- prepass: mask int32 -> bits (diag OR-folded) ----------------
__global__ __launch_bounds__(256)
void cvt_mask(const int* __restrict__ m, unsigned long long* __restrict__ out, int ngroups)
{
  const int lane = threadIdx.x & 63;
  int gid = (blockIdx.x * blockDim.x + threadIdx.x) >> 6;
  const int stride = (gridDim.x * blockDim.x) >> 6;
  for (; gid < ngroups; gid += stride) {
    const size_t base = (size_t)gid * 64;
    const int rem = (int)(base & ((size_t)Sc * Sc - 1));
    const int srow = rem >> 11;
    const int k = (rem & (Sc - 1)) + lane;
    const bool pred = (m[base + lane] != 0) || (k == srow);
    unsigned long long bal = __ballot(pred);
    if (lane == 0) out[gid] = bal;
  }
}

// ---------------- 128x128-tile bf16 NT GEMM (m97 structure) ----------------
struct GArgs {
  const unsigned short* A[3];
  const unsigned short* W[3];
  const float* bias[3];
  void* C[3];
  int mode[3];
};

__global__ __launch_bounds__(256)
void gemm128(GArgs ga)
{
  __shared__ unsigned short As[128][64];   // XOR-swizzled rows (128 B, 8 slots)
  __shared__ unsigned short Bs[128][64];

  constexpr int K = 512, N = 512;
  const int z = blockIdx.z;
  const unsigned short* Ap = ga.A[z];
  const unsigned short* Wp = ga.W[z];
  const float* bias = ga.bias[z];
  const int mode = ga.mode[z];

  const int tid = threadIdx.x, lane = tid & 63, w = tid >> 6;
  const int m0 = blockIdx.x * 128, n0 = blockIdx.y * 128;
  const int wm = w >> 1, wn = w & 1;
  const int colb = lane & 15, hi = lane >> 4, rowb = hi * 4;
  const int swz = (colb & 7) << 4;

  f32x4 acc[4][4];
#pragma unroll
  for (int i = 0; i < 4; ++i)
#pragma unroll
    for (int j = 0; j < 4; ++j) acc[i][j] = (f32x4){0.f, 0.f, 0.f, 0.f};

  const int lrow8 = lane >> 3;
  const int cb = ((lane & 7) * 16) ^ (lrow8 << 4);

  for (int k0 = 0; k0 < K; k0 += 64) {
    if (k0) __syncthreads();
#pragma unroll
    for (int i = 0; i < 4; ++i) {
      const int obase = w * 1024 + i * 4096;
      const int row = w * 8 + i * 32 + lrow8;
      const unsigned short* asrc = Ap + (size_t)(m0 + row) * K + k0 + (cb >> 1);
      const unsigned short* bsrc = Wp + (size_t)(n0 + row) * K + k0 + (cb >> 1);
      __builtin_amdgcn_global_load_lds((g_void*)asrc, (lds_void*)((char*)&As[0][0] + obase), 16, 0, 0);
      __builtin_amdgcn_global_load_lds((g_void*)bsrc, (lds_void*)((char*)&Bs[0][0] + obase), 16, 0, 0);
    }
    asm volatile("s_waitcnt vmcnt(0)" ::: "memory");
    __syncthreads();

    char* ab = (char*)&As[0][0];
    char* bb = (char*)&Bs[0][0];
#pragma unroll
    for (int kk = 0; kk < 2; ++kk) {
      bf16x8 af[4], bfr[4];
#pragma unroll
      for (int mf = 0; mf < 4; ++mf) {
        const int ar = wm * 64 + mf * 16 + colb;
        af[mf] = *(const bf16x8*)(ab + ar * 128 + ((kk * 64 + hi * 16) ^ swz));
      }
#pragma unroll
      for (int nf = 0; nf < 4; ++nf) {
        const int br = wn * 64 + nf * 16 + colb;
        bfr[nf] = *(const bf16x8*)(bb + br * 128 + ((kk * 64 + hi * 16) ^ swz));
      }
#pragma unroll
      for (int mf = 0; mf < 4; ++mf)
#pragma unroll
        for (int nf = 0; nf < 4; ++nf)
          acc[mf][nf] = __builtin_amdgcn_mfma_f32_16x16x32_bf16(af[mf], bfr[nf], acc[mf][nf], 0, 0, 0);
    }
  }

#pragma unroll
  for (int nf = 0; nf < 4; ++nf) {
    const int gn = n0 + wn * 64 + nf * 16 + colb;
    const float bv = bias[gn];
    if (mode == 1) {
      unsigned short* Cp = (unsigned short*)ga.C[z];
#pragma unroll
      for (int mf = 0; mf < 4; ++mf) {
        const int gm = m0 + wm * 64 + mf * 16 + rowb;
        const int bb_ = gm >> 11, ss = gm & (Sc - 1);
        us4 vv;
#pragma unroll
        for (int rr = 0; rr < 4; ++rr) vv.u[rr] = f2bf(acc[mf][nf][rr] + bv);
        *(us4*)(Cp + ((size_t)bb_ * N + gn) * Sc + ss) = vv;
      }
    } else if (mode == 0) {
      unsigned short* Cp = (unsigned short*)ga.C[z];
#pragma unroll
      for (int mf = 0; mf < 4; ++mf)
#pragma unroll
        for (int rr = 0; rr < 4; ++rr) {
          const int gm = m0 + wm * 64 + mf * 16 + rowb + rr;
          Cp[(size_t)gm * N + gn] = f2bf(acc[mf][nf][rr] + bv);
        }
    } else {
      float* Cp = (float*)ga.C[z];
#pragma unroll
      for (int mf = 0; mf < 4; ++mf)
#pragma unroll
        for (int rr = 0; rr < 4; ++rr) {
          const int gm = m0 + wm * 64 + mf * 16 + rowb + rr;
          Cp[(size_t)gm * N + gn] = acc[mf][nf][rr] + bv;
        }
    }
  }
}

// ---------------- split-K flash attention (S^T form, exp2 domain, defer-max) ----------------
// grid (B*H, S/64, SPLIT). Partials: Pacc[blk][d=64][q=64] (O^T), Pml[blk][2][64] (m in log2 domain).
__global__ __launch_bounds__(256, 4)
void attn_split(const unsigned short* __restrict__ Qb,
                const unsigned short* __restrict__ Kb,
                const unsigned short* __restrict__ Vt,
                const float* __restrict__ Gf,
                const unsigned long long* __restrict__ Mb,
                float* __restrict__ Pacc,
                float* __restrict__ Pml)
{
  __shared__ unsigned short Ks[2][64][64];   // [k][dk], XOR-swizzled rows
  __shared__ unsigned short Vs[2][64][64];   // [dk][k], XOR-swizzled rows
  __shared__ unsigned short Ps[4][16][64];   // per-wave P [q][k], XOR-swizzled rows

  const int tid = threadIdx.x, lane = tid & 63, wid = tid >> 6;
  const int bh = blockIdx.x, b = bh >> 3, h = bh & 7;
  const int qt = blockIdx.y, q0 = qt * 64;
  const int sp = blockIdx.z;
  const int kt0 = sp * KT_PER;

  const int colb = lane & 15;
  const int hi = lane >> 4;
  const int rowb = hi * 4;
  const int c3s = (colb & 7) << 4;

  // Q fragment = B-operand of S^T mfma (lane holds Q[q=wid*16+colb][d=hi*8+j])
  bf16x8 qf[2];
  {
    const unsigned short* qp = Qb + ((size_t)(b * Sc + q0 + wid * 16 + colb) * Dc + h * DKc + hi * 8);
    qf[0] = *(const bf16x8*)qp;
    qf[1] = *(const bf16x8*)(qp + 32);
  }

  f32x4 acc[4] = {{0,0,0,0},{0,0,0,0},{0,0,0,0},{0,0,0,0}};   // acc[n][rr] = O^T[n*16+rowb+rr][q]
  float mrun = -1e30f, lrun = 0.f;                             // log2-domain per-q scalars

  auto stageKV = [&](int bufI, int kt) {
    const int k0 = kt * 64;
#pragma unroll
    for (int i = 0; i < 2; ++i) {
      const int obase = wid * 1024 + i * 4096;
      const int row = (obase >> 7) + (lane >> 3);
      const int cb = ((lane & 7) * 16) ^ ((row & 7) << 4);
      const unsigned short* ksrc = Kb + (size_t)(b * Sc + k0 + row) * Dc + h * DKc + (cb >> 1);
      const unsigned short* vsrc = Vt + ((size_t)b * Dc + h * DKc + row) * Sc + k0 + (cb >> 1);
      __builtin_amdgcn_global_load_lds((g_void*)ksrc, (lds_void*)((char*)&Ks[bufI][0][0] + obase), 16, 0, 0);
      __builtin_amdgcn_global_load_lds((g_void*)vsrc, (lds_void*)((char*)&Vs[bufI][0][0] + obase), 16, 0, 0);
    }
  };

  const unsigned long long* mrow = Mb + ((size_t)(b * Sc) + q0 + wid * 16 + colb) * NKT;
  const float* grow = Gf + ((size_t)(b * Sc) + q0 + wid * 16 + colb) * Sc + hi * 4;

  f32x4 gcur[4];
  unsigned long long mcur;
  auto loadGM = [&](int kt, f32x4* gv, unsigned long long& mm) {
    const float* gp = grow + kt * 64;
#pragma unroll
    for (int n = 0; n < 4; ++n) gv[n] = *(const f32x4*)(gp + n * 16);
    mm = mrow[kt];
  };

  stageKV(0, kt0);
  loadGM(kt0, gcur, mcur);
  asm volatile("s_waitcnt vmcnt(0)" ::: "memory");
  __syncthreads();

  int buf = 0;
  char* psbase = (char*)&Ps[wid][0][0];

  for (int j = 0; j < KT_PER; ++j) {
    const int kt = kt0 + j;
    f32x4 gnx[4]; unsigned long long mn_;
    if (j + 1 < KT_PER) {
      stageKV(buf ^ 1, kt + 1);
      loadGM(kt + 1, gnx, mn_);
    }

    // S^T = K Q^T : sf[n][rr] = S[q=colb][k = n*16 + hi*4 + rr]
    f32x4 sf[4] = {{0,0,0,0},{0,0,0,0},{0,0,0,0},{0,0,0,0}};
    char* ksb = (char*)&Ks[buf][0][0];
#pragma unroll
    for (int kk = 0; kk < 2; ++kk) {
#pragma unroll
      for (int n = 0; n < 4; ++n) {
        const int krow = n * 16 + colb;
        bf16x8 kf = *(const bf16x8*)(ksb + krow * 128 + ((kk * 64 + hi * 16) ^ ((krow & 7) << 4)));
        sf[n] = __builtin_amdgcn_mfma_f32_16x16x32_bf16(kf, qf[kk], sf[n], 0, 0, 0);
      }
    }

    // scale into exp2 domain + mask (bits include diagonal); k-bit = n*16 + hi*4 + rr
    const unsigned long long msh = mcur >> (hi * 4);
#pragma unroll
    for (int n = 0; n < 4; ++n) {
#pragma unroll
      for (int rr = 0; rr < 4; ++rr) {
        const bool allowed = ((unsigned int)(msh >> (n * 16 + rr)) & 1u) != 0u;
        sf[n][rr] = allowed ? sf[n][rr] * CSC : -1e30f;
      }
    }

    // row max over this lane's 16 values + 4-lane combine
    float tm = sf[0][0];
#pragma unroll
    for (int n = 0; n < 4; ++n)
#pragma unroll
      for (int rr = 0; rr < 4; ++rr) tm = fmaxf(tm, sf[n][rr]);
    tm = fmaxf(tm, __shfl_xor(tm, 16));
    tm = fmaxf(tm, __shfl_xor(tm, 32));

    // defer-max: rescale only when some row grows by >8 (log2); P bounded by 2^8
    if (__any(tm > mrun + 8.f)) {
      const float mnew = fmaxf(mrun, tm);
      const float alpha = __builtin_amdgcn_exp2f(mrun - mnew);
      mrun = mnew;
#pragma unroll
      for (int n = 0; n < 4; ++n)
#pragma unroll
        for (int rr = 0; rr < 4; ++rr) acc[n][rr] *= alpha;
      lrun *= alpha;
    }

    // p = exp2(s2 - m); pack p*g pairs; row sum
    float rsum = 0.f;
    unsigned int pw[8];
#pragma unroll
    for (int n = 0; n < 4; ++n) {
#pragma unroll
      for (int s2 = 0; s2 < 2; ++s2) {
        const float p0 = __builtin_amdgcn_exp2f(sf[n][s2 * 2]     - mrun);
        const float p1 = __builtin_amdgcn_exp2f(sf[n][s2 * 2 + 1] - mrun);
        rsum += p0 + p1;
        const float q0v = p0 * gcur[n][s2 * 2], q1v = p1 * gcur[n][s2 * 2 + 1];
        asm("v_cvt_pk_bf16_f32 %0, %1, %2" : "=v"(pw[n * 2 + s2]) : "v"(q0v), "v"(q1v));
      }
    }
    rsum += __shfl_xor(rsum, 16);
    rsum += __shfl_xor(rsum, 32);
    lrun += rsum;

    // store P [q=colb][k] as 4x ds_write_b64
#pragma unroll
    for (int n = 0; n < 4; ++n) {
      const unsigned long long w64 = ((unsigned long long)pw[n * 2 + 1] << 32) | pw[n * 2];
      *(unsigned long long*)(psbase + colb * 128 + ((n * 32 + hi * 8) ^ c3s)) = w64;
    }

    // acc += V^T P^T  (O^T layout; Ps wave-private)
    char* vsb = (char*)&Vs[buf][0][0];
#pragma unroll
    for (int kk = 0; kk < 2; ++kk) {
      bf16x8 pf = *(const bf16x8*)(psbase + colb * 128 + ((kk * 64 + hi * 16) ^ c3s));
#pragma unroll
      for (int n = 0; n < 4; ++n) {
        const int vrow = n * 16 + colb;
        bf16x8 vf = *(const bf16x8*)(vsb + vrow * 128 + ((kk * 64 + hi * 16) ^ ((vrow & 7) << 4)));
        acc[n] = __builtin_amdgcn_mfma_f32_16x16x32_bf16(vf, pf, acc[n], 0, 0, 0);
      }
    }

    asm volatile("s_waitcnt vmcnt(0)" ::: "memory");
    __syncthreads();
    buf ^= 1;
    if (j + 1 < KT_PER) {
#pragma unroll
      for (int n = 0; n < 4; ++n) gcur[n] = gnx[n];
      mcur = mn_;
    }
  }

  // write partials (O^T layout: [d][q])
  const size_t blin = ((size_t)bh * 32 + qt) * SPLIT + sp;
  float* pa = Pacc + blin * 4096;
#pragma unroll
  for (int n = 0; n < 4; ++n)
#pragma unroll
    for (int rr = 0; rr < 4; ++rr)
      pa[(size_t)(n * 16 + rowb + rr) * 64 + wid * 16 + colb] = acc[n][rr];
  if (hi == 0) {
    float* pm = Pml + blin * 128;
    pm[wid * 16 + colb] = mrun;
    pm[64 + wid * 16 + colb] = lrun;
  }
}

// ---------------- recombine split partials -> bf16 X (m in log2 domain) ----------------
__global__ __launch_bounds__(256)
void attn_reduce(const float* __restrict__ Pacc, const float* __restrict__ Pml,
                 unsigned short* __restrict__ Xb)
{
  const int gidx = blockIdx.x;      // bh*32 + qt
  const int bh = gidx >> 5, qt = gidx & 31;
  const int b = bh >> 3, h = bh & 7;
  const int tid = threadIdx.x;
  const int qi = tid & 63;
  const int d0 = (tid >> 6) * 16;
  const size_t pb = (size_t)gidx * SPLIT;

  float m[SPLIT], l[SPLIT];
  float mstar = -3.0e38f;
#pragma unroll
  for (int s = 0; s < SPLIT; ++s) {
    m[s] = Pml[(pb + s) * 128 + qi];
    l[s] = Pml[(pb + s) * 128 + 64 + qi];
    mstar = fmaxf(mstar, m[s]);
  }
  float w[SPLIT], denom = 0.f;
#pragma unroll
  for (int s = 0; s < SPLIT; ++s) { w[s] = __builtin_amdgcn_exp2f(m[s] - mstar); denom += w[s] * l[s]; }
  const float inv = 1.0f / denom;

  unsigned short vals[16];
#pragma unroll
  for (int j = 0; j < 16; ++j) {
    float a = 0.f;
#pragma unroll
    for (int s = 0; s < SPLIT; ++s)
      a += w[s] * Pacc[(pb + s) * 4096 + (size_t)(d0 + j) * 64 + qi];
    vals[j] = f2bf(a * inv);
  }
  unsigned short* xp = Xb + ((size_t)(b * Sc) + qt * 64 + qi) * Dc + h * DKc + d0;
  *(us8*)xp = *(us8*)&vals[0];
  *(us8*)(xp + 8) = *(us8*)&vals[8];
}

extern "C" void kernel_launch(void* const* d_in, const int* in_sizes, int n_in,
                              void* d_out, int out_size, void* d_ws, size_t ws_size,
                              hipStream_t stream)
{
  const float* query = (const float*)d_in[0];
  const float* key_  = (const float*)d_in[1];
  const float* value = (const float*)d_in[2];
  const float* gprob = (const float*)d_in[3];
  const int*   mask  = (const int*)d_in[4];
  const float* Wq = (const float*)d_in[5];
  const float* bq = (const float*)d_in[6];
  const float* Wk = (const float*)d_in[7];
  const float* bk = (const float*)d_in[8];
  const float* Wv = (const float*)d_in[9];
  const float* bv = (const float*)d_in[10];
  const float* Wo = (const float*)d_in[11];
  const float* bo = (const float*)d_in[12];
  float* out = (float*)d_out;

  const size_t elems = (size_t)Bc * Sc * Dc;     // 2 Mi
  const size_t gelems = (size_t)Bc * Sc * Sc;    // 8 Mi
  const size_t welems = (size_t)Dc * Dc;         // 256 Ki

  char* base = (char*)d_ws;
  unsigned short* Qb = (unsigned short*)(base);                    // 4 MB
  unsigned short* Kb = Qb + elems;                                 // 4 MB
  unsigned short* Vt = Kb + elems;                                 // 4 MB
  unsigned short* Xb = Vt + elems;                                 // 4 MB
  unsigned long long* Mbits = (unsigned long long*)(Xb + elems);   // 1 MB
  char* shared_region = (char*)(Mbits + gelems / 64);
  // shared region: first bf16 copies of q/k/v inputs, later split partials
  unsigned short* Ain = (unsigned short*)shared_region;            // 4 MB
  unsigned short* Bin = Ain + elems;                               // 4 MB
  unsigned short* Cin = Bin + elems;                               // 4 MB
  float* Pacc = (float*)shared_region;                             // 16.8 MB
  float* Pml  = Pacc + (size_t)(Bc * Hc) * 32 * SPLIT * 4096;      // 0.5 MB
  // weights (bf16) past the shared region's max extent
  unsigned short* Wqb = (unsigned short*)(shared_region + (18u << 20));
  unsigned short* Wkb = Wqb + welems;
  unsigned short* Wvb = Wkb + welems;
  unsigned short* Wob = Wvb + welems;

  // prepasses
  CArgs ca;
  ca.src[0] = query; ca.dst[0] = Ain; ca.n8[0] = (int)(elems / 8);
  ca.src[1] = key_;  ca.dst[1] = Bin; ca.n8[1] = (int)(elems / 8);
  ca.src[2] = value; ca.dst[2] = Cin; ca.n8[2] = (int)(elems / 8);
  ca.src[3] = Wq;    ca.dst[3] = Wqb; ca.n8[3] = (int)(welems / 8);
  ca.src[4] = Wk;    ca.dst[4] = Wkb; ca.n8[4] = (int)(welems / 8);
  ca.src[5] = Wv;    ca.dst[5] = Wvb; ca.n8[5] = (int)(welems / 8);
  ca.src[6] = Wo;    ca.dst[6] = Wob; ca.n8[6] = (int)(welems / 8);
  hipLaunchKernelGGL(cvt_multi, dim3(128, 7), dim3(256), 0, stream, ca);
  hipLaunchKernelGGL(cvt_mask, dim3(2048), dim3(256), 0, stream, mask, Mbits, (int)(gelems / 64));

  // fused Q/K/V projections
  GArgs gq;
  gq.A[0] = Ain; gq.W[0] = Wqb; gq.bias[0] = bq; gq.C[0] = (void*)Qb; gq.mode[0] = 0;
  gq.A[1] = Bin; gq.W[1] = Wkb; gq.bias[1] = bk; gq.C[1] = (void*)Kb; gq.mode[1] = 0;
  gq.A[2] = Cin; gq.W[2] = Wvb; gq.bias[2] = bv; gq.C[2] = (void*)Vt; gq.mode[2] = 1;
  hipLaunchKernelGGL(gemm128, dim3(32, 4, 3), dim3(256), 0, stream, gq);

  dim3 ga(Bc * Hc, Sc / 64, SPLIT);
  hipLaunchKernelGGL(attn_split, ga, dim3(256), 0, stream, Qb, Kb, Vt, gprob, Mbits, Pacc, Pml);
  hipLaunchKernelGGL(attn_reduce, dim3(Bc * Hc * 32), dim3(256), 0, stream, Pacc, Pml, Xb);

  // output projection
  GArgs go;
  go.A[0] = Xb; go.W[0] = Wob; go.bias[0] = bo; go.C[0] = (void*)out; go.mode[0] = 2;
  go.A[1] = Xb; go.W[1] = Wob; go.bias[1] = bo; go.C[1] = (void*)out; go.mode[1] = 2;
  go.A[2] = Xb; go.W[2] = Wob; go.bias[2] = bo; go.C[2] = (void*)out; go.mode[2] = 2;
  hipLaunchKernelGGL(gemm128, dim3(32, 4, 1), dim3(256), 0, stream, go);
}